// Round 7
// baseline (734.428 us; speedup 1.0000x reference)
//
#include <hip/hip_runtime.h>
#include <math.h>

#define BB 64
#define DD 128
#define NN 400
#define MM 50
#define HH 8
#define KDIM 16
#define NC 4
#define KW 7
#define CH 200   // attention key-chunk: LDS 26.4 KB

#define SZ_C (BB * DD * NN)   // 3,276,800
#define SZ_Q (BB * DD * MM)   //   409,600
#define SSTAT (BB * NN + BB * MM)  // 28,800; q stats at offset BB*NN

// ---------------- canonical weight transpose: Wcan[m][d][e] ----------------
__global__ void k_transposeW(const float* __restrict__ pw_w, const float* __restrict__ Wo,
                             const float* __restrict__ Wfc, const float* __restrict__ Wq,
                             const float* __restrict__ Wk, const float* __restrict__ Wv,
                             float* __restrict__ Wcan) {
  int idx = blockIdx.x * 256 + threadIdx.x;
  if (idx >= 9 * 16384) return;
  int m = idx >> 14;
  int r = idx & 16383;
  int d = r >> 7, e = r & 127;
  float v;
  if (m < 4) v = pw_w[m * 16384 + e * 128 + d];
  else if (m == 4) v = Wo[d * 128 + e];
  else if (m == 5) v = Wfc[e * 128 + d];
  else {
    const float* W = (m == 6) ? Wq : (m == 7) ? Wk : Wv;
    v = W[((e >> 4) * 128 + d) * 16 + (e & 15)];
  }
  Wcan[idx] = v;
}

// ---------------- fused PE add + LN stats ----------------
__global__ void k_pestats(const float* __restrict__ xC, const float* __restrict__ xQ,
                          float* __restrict__ yC, float* __restrict__ yQ,
                          float* __restrict__ mu, float* __restrict__ inv) {
  int blk = blockIdx.x;
  const float* x; float* y; int L, l0, b, soff;
  if (blk < 448) { b = blk / 7; l0 = (blk % 7) * 64; x = xC; y = yC; L = NN; soff = 0; }
  else { b = blk - 448; l0 = 0; x = xQ; y = yQ; L = MM; soff = BB * NN; }
  int tid = threadIdx.x;
  int ll = tid & 63;
  int dq = tid >> 6;
  int l = l0 + ll;
  __shared__ float s_sum[4][64], s_sq[4][64];
  float sum = 0.f, sq = 0.f;
  if (l < L) {
    const float* px = x + (size_t)b * DD * L + l;
    float* py = y + (size_t)b * DD * L + l;
    for (int d = dq * 32; d < dq * 32 + 32; ++d) {
      int de = d & ~1;
      float freq = __expf((float)de * (-9.210340371976184f / 128.0f));
      float ph = (d & 1) ? 1.5707963267948966f : 0.0f;
      float v = px[(size_t)d * L] + sinf((float)l * freq + ph);
      py[(size_t)d * L] = v;
      sum += v; sq += v * v;
    }
  }
  s_sum[dq][ll] = sum; s_sq[dq][ll] = sq;
  __syncthreads();
  if (dq == 0 && l < L) {
    float ts = s_sum[0][ll] + s_sum[1][ll] + s_sum[2][ll] + s_sum[3][ll];
    float tq = s_sq[0][ll] + s_sq[1][ll] + s_sq[2][ll] + s_sq[3][ll];
    float m = ts * (1.0f / 128.0f);
    float var = (tq - 128.0f * m * m) * (1.0f / 127.0f);
    float sd = sqrtf(fmaxf(var, 0.f));
    mu[soff + b * L + l] = m;
    inv[soff + b * L + l] = 1.0f / (sd + 1e-6f);
  }
}

// ---------------- fused conv layer, 64-col tiles (512 blocks = 2/CU) ----------------
__global__ __launch_bounds__(256, 2) void k_convgemm(
    const float* __restrict__ xC, const float* __restrict__ xQ,
    float* __restrict__ outC, float* __restrict__ outQ,
    const float* __restrict__ Wc, const float* __restrict__ pwb,
    const float* __restrict__ dww, const float* __restrict__ dwb,
    const float* __restrict__ muI, const float* __restrict__ invI,
    float* __restrict__ muO, float* __restrict__ invO,
    const float* __restrict__ g, const float* __restrict__ beta) {
  int blk = blockIdx.x;
  int b = blk >> 3, tile = blk & 7;
  const float* x; float* out; int L, l0, soff;
  if (tile < 7) { x = xC; out = outC; L = NN; l0 = tile * 64; soff = 0; }
  else { x = xQ; out = outQ; L = MM; l0 = 0; soff = BB * NN; }
  __shared__ float Wl[32 * 128];
  __shared__ float Xl[32 * 64];
  __shared__ float Sm[70], Si[70];   // stats halo [l0-3, l0+67)
  int tid = threadIdx.x;
  const float* xb = x + (size_t)b * DD * L;
  for (int t = tid; t < 70; t += 256) {
    int gl = l0 + t - 3;
    bool ok = (gl >= 0 && gl < L);
    Sm[t] = ok ? muI[soff + b * L + gl] : 0.f;
    Si[t] = ok ? invI[soff + b * L + gl] : 0.f;
  }
  float acc[8][4];
  #pragma unroll
  for (int i = 0; i < 8; ++i)
    #pragma unroll
    for (int j = 0; j < 4; ++j) acc[i][j] = 0.f;
  __syncthreads();
  for (int kc = 0; kc < 4; ++kc) {
    int d0 = kc * 32;
    #pragma unroll
    for (int i = 0; i < 4; ++i) {
      int idx = i * 256 + tid;
      ((float4*)Wl)[idx] = ((const float4*)Wc)[(size_t)d0 * 32 + idx];
    }
    #pragma unroll
    for (int r = 0; r < 2; ++r) {
      int k = r * 16 + (tid >> 4);
      int d = d0 + k;
      int c0 = (tid & 15) * 4;
      const float* xrow = xb + (size_t)d * L;
      float gd = g[d], bd = beta[d];
      float wv[7];
      #pragma unroll
      for (int u = 0; u < 7; ++u) wv[u] = dww[d * 7 + u];
      float dbv = dwb[d];
      float xw[10];
      int gbase = l0 + c0 - 3;
      if (gbase >= 1 && gbase + 11 <= L && (((unsigned)(d * L + gbase - 1)) & 3u) == 0u) {
        const float4* p = (const float4*)&xrow[gbase - 1];
        float4 A = p[0], Bv = p[1], Cv = p[2];
        float xr[12] = {A.x, A.y, A.z, A.w, Bv.x, Bv.y, Bv.z, Bv.w, Cv.x, Cv.y, Cv.z, Cv.w};
        #pragma unroll
        for (int s = 0; s < 10; ++s)
          xw[s] = gd * (xr[s + 1] - Sm[c0 + s]) * Si[c0 + s] + bd;
      } else {
        #pragma unroll
        for (int s = 0; s < 10; ++s) {
          int gl = gbase + s;
          float v = 0.f;
          if (gl >= 0 && gl < L)
            v = gd * (xrow[gl] - Sm[c0 + s]) * Si[c0 + s] + bd;
          xw[s] = v;
        }
      }
      float4 o;
      o.x = dbv; o.y = dbv; o.z = dbv; o.w = dbv;
      #pragma unroll
      for (int u = 0; u < 7; ++u) {
        o.x += wv[u] * xw[u];
        o.y += wv[u] * xw[u + 1];
        o.z += wv[u] * xw[u + 2];
        o.w += wv[u] * xw[u + 3];
      }
      *(float4*)&Xl[k * 64 + c0] = o;
    }
    __syncthreads();
    int e0 = (tid >> 4) * 8, cq = (tid & 15) * 4;
    for (int k = 0; k < 32; ++k) {
      const float4* wp = (const float4*)&Wl[k * 128 + e0];
      float4 w0 = wp[0], w1 = wp[1];
      float4 xv = *(const float4*)&Xl[k * 64 + cq];
      float we[8] = {w0.x, w0.y, w0.z, w0.w, w1.x, w1.y, w1.z, w1.w};
      float xe[4] = {xv.x, xv.y, xv.z, xv.w};
      #pragma unroll
      for (int i = 0; i < 8; ++i)
        #pragma unroll
        for (int j = 0; j < 4; ++j) acc[i][j] += we[i] * xe[j];
    }
    __syncthreads();
  }
  int e0 = (tid >> 4) * 8, cq = (tid & 15) * 4;
  float ssum[4], ssq[4];
  #pragma unroll
  for (int j = 0; j < 4; ++j) { ssum[j] = 0.f; ssq[j] = 0.f; }
  #pragma unroll
  for (int i = 0; i < 8; ++i) {
    float bi = pwb[e0 + i];
    float* po = out + ((size_t)b * DD + e0 + i) * L;
    const float* pr = xb + (size_t)(e0 + i) * L;
    #pragma unroll
    for (int j = 0; j < 4; ++j) {
      int l = l0 + cq + j;
      if (l < L) {
        float v = fmaxf(acc[i][j] + bi, 0.f) + pr[l];
        po[l] = v;
        ssum[j] += v; ssq[j] += v * v;
      }
    }
  }
  int grp = tid >> 4;
  #pragma unroll
  for (int j = 0; j < 4; ++j) {
    Xl[grp * 64 + cq + j] = ssum[j];
    Wl[grp * 64 + cq + j] = ssq[j];
  }
  __syncthreads();
  if (tid < 64) {
    int l = l0 + tid;
    if (l < L) {
      float ts = 0.f, tq = 0.f;
      #pragma unroll
      for (int gg = 0; gg < 16; ++gg) { ts += Xl[gg * 64 + tid]; tq += Wl[gg * 64 + tid]; }
      float m = ts * (1.0f / 128.0f);
      float var = (tq - 128.0f * m * m) * (1.0f / 127.0f);
      float sd = sqrtf(fmaxf(var, 0.f));
      muO[soff + b * L + l] = m;
      invO[soff + b * L + l] = 1.0f / (sd + 1e-6f);
    }
  }
}

// ---------------- 128x64 GEMM tiles, 512 blocks ----------------
template <int LNF, int ACT, int STATS>
__global__ __launch_bounds__(256) void k_gemm64(
    const float* __restrict__ xC, const float* __restrict__ xQ,
    float* __restrict__ outC, float* __restrict__ outQ,
    const float* __restrict__ Wc, const float* __restrict__ bias,
    const float* __restrict__ mu, const float* __restrict__ inv,
    float* __restrict__ muO, float* __restrict__ invO,
    const float* __restrict__ g, const float* __restrict__ beta) {
  int blk = blockIdx.x;
  int b = blk >> 3, tile = blk & 7;
  const float* x; float* out; int L, l0, soff;
  if (tile < 7) { x = xC; out = outC; L = NN; l0 = tile * 64; soff = 0; }
  else { x = xQ; out = outQ; L = MM; l0 = 0; soff = BB * NN; }
  __shared__ float Wl[32 * 128];
  __shared__ float Xl[32 * 64];
  int tid = threadIdx.x;
  float acc[8][4];
  #pragma unroll
  for (int i = 0; i < 8; ++i)
    #pragma unroll
    for (int j = 0; j < 4; ++j) acc[i][j] = 0.f;
  const float* xb = x + (size_t)b * DD * L;
  const float* pmu = mu + soff + b * L;
  const float* pin = inv + soff + b * L;
  for (int kc = 0; kc < 4; ++kc) {
    int d0 = kc * 32;
    #pragma unroll
    for (int i = 0; i < 4; ++i) {
      int idx = i * 256 + tid;
      ((float4*)Wl)[idx] = ((const float4*)Wc)[(size_t)d0 * 32 + idx];
    }
    #pragma unroll
    for (int t = 0; t < 8; ++t) {
      int idx = t * 256 + tid;
      int k = idx >> 6, l = idx & 63;
      float v = 0.f;
      int gl = l0 + l;
      if (gl < L) {
        v = xb[(size_t)(d0 + k) * L + gl];
        if (LNF) v = g[d0 + k] * (v - pmu[gl]) * pin[gl] + beta[d0 + k];
      }
      Xl[idx] = v;
    }
    __syncthreads();
    int e0 = (tid >> 4) * 8, cq = (tid & 15) * 4;
    for (int k = 0; k < 32; ++k) {
      const float4* wp = (const float4*)&Wl[k * 128 + e0];
      float4 w0 = wp[0], w1 = wp[1];
      float4 xv = *(const float4*)&Xl[k * 64 + cq];
      float we[8] = {w0.x, w0.y, w0.z, w0.w, w1.x, w1.y, w1.z, w1.w};
      float xe[4] = {xv.x, xv.y, xv.z, xv.w};
      #pragma unroll
      for (int i = 0; i < 8; ++i)
        #pragma unroll
        for (int j = 0; j < 4; ++j) acc[i][j] += we[i] * xe[j];
    }
    __syncthreads();
  }
  int e0 = (tid >> 4) * 8, cq = (tid & 15) * 4;
  float ssum[4], ssq[4];
  #pragma unroll
  for (int j = 0; j < 4; ++j) { ssum[j] = 0.f; ssq[j] = 0.f; }
  #pragma unroll
  for (int i = 0; i < 8; ++i) {
    float bi = bias[e0 + i];
    float* po = out + ((size_t)b * DD + e0 + i) * L;
    #pragma unroll
    for (int j = 0; j < 4; ++j) {
      int l = l0 + cq + j;
      if (l < L) {
        float v = acc[i][j] + bi;
        if (ACT != 0) v += po[l];
        po[l] = v;
        if (STATS) { ssum[j] += v; ssq[j] += v * v; }
      }
    }
  }
  if (STATS) {
    int grp = tid >> 4;
    #pragma unroll
    for (int j = 0; j < 4; ++j) {
      Xl[grp * 64 + cq + j] = ssum[j];
      Wl[grp * 64 + cq + j] = ssq[j];
    }
    __syncthreads();
    if (tid < 64) {
      int l = l0 + tid;
      if (l < L) {
        float ts = 0.f, tq = 0.f;
        #pragma unroll
        for (int gg = 0; gg < 16; ++gg) { ts += Xl[gg * 64 + tid]; tq += Wl[gg * 64 + tid]; }
        float m = ts * (1.0f / 128.0f);
        float var = (tq - 128.0f * m * m) * (1.0f / 127.0f);
        float sd = sqrtf(fmaxf(var, 0.f));
        muO[soff + b * L + l] = m;
        invO[soff + b * L + l] = 1.0f / (sd + 1e-6f);
      }
    }
  }
}

// ---------------- fused QKV GEMM: 3 x 512 blocks ----------------
__global__ __launch_bounds__(256) void k_gemm_qkv(
    const float* __restrict__ xC, const float* __restrict__ xQ,
    float* __restrict__ o1C, float* __restrict__ o1Q,
    float* __restrict__ o2C, float* __restrict__ o2Q,
    float* __restrict__ o3C, float* __restrict__ o3Q,
    const float* __restrict__ Wcan,
    const float* __restrict__ bq, const float* __restrict__ bk, const float* __restrict__ bv,
    const float* __restrict__ mu, const float* __restrict__ inv,
    const float* __restrict__ g, const float* __restrict__ beta) {
  int blk0 = blockIdx.x;
  int grp = blk0 >> 9;
  int blk = blk0 & 511;
  const float* Wc = Wcan + (size_t)(6 + grp) * 16384;
  const float* bias = (grp == 0) ? bq : (grp == 1) ? bk : bv;
  float* oC = (grp == 0) ? o1C : (grp == 1) ? o2C : o3C;
  float* oQ = (grp == 0) ? o1Q : (grp == 1) ? o2Q : o3Q;
  int b = blk >> 3, tile = blk & 7;
  const float* x; float* out; int L, l0, soff;
  if (tile < 7) { x = xC; out = oC; L = NN; l0 = tile * 64; soff = 0; }
  else { x = xQ; out = oQ; L = MM; l0 = 0; soff = BB * NN; }
  __shared__ float Wl[32 * 128];
  __shared__ float Xl[32 * 64];
  int tid = threadIdx.x;
  float acc[8][4];
  #pragma unroll
  for (int i = 0; i < 8; ++i)
    #pragma unroll
    for (int j = 0; j < 4; ++j) acc[i][j] = 0.f;
  const float* xb = x + (size_t)b * DD * L;
  const float* pmu = mu + soff + b * L;
  const float* pin = inv + soff + b * L;
  for (int kc = 0; kc < 4; ++kc) {
    int d0 = kc * 32;
    #pragma unroll
    for (int i = 0; i < 4; ++i) {
      int idx = i * 256 + tid;
      ((float4*)Wl)[idx] = ((const float4*)Wc)[(size_t)d0 * 32 + idx];
    }
    #pragma unroll
    for (int t = 0; t < 8; ++t) {
      int idx = t * 256 + tid;
      int k = idx >> 6, l = idx & 63;
      float v = 0.f;
      int gl = l0 + l;
      if (gl < L) {
        v = xb[(size_t)(d0 + k) * L + gl];
        v = g[d0 + k] * (v - pmu[gl]) * pin[gl] + beta[d0 + k];
      }
      Xl[idx] = v;
    }
    __syncthreads();
    int e0 = (tid >> 4) * 8, cq = (tid & 15) * 4;
    for (int k = 0; k < 32; ++k) {
      const float4* wp = (const float4*)&Wl[k * 128 + e0];
      float4 w0 = wp[0], w1 = wp[1];
      float4 xv = *(const float4*)&Xl[k * 64 + cq];
      float we[8] = {w0.x, w0.y, w0.z, w0.w, w1.x, w1.y, w1.z, w1.w};
      float xe[4] = {xv.x, xv.y, xv.z, xv.w};
      #pragma unroll
      for (int i = 0; i < 8; ++i)
        #pragma unroll
        for (int j = 0; j < 4; ++j) acc[i][j] += we[i] * xe[j];
    }
    __syncthreads();
  }
  int e0 = (tid >> 4) * 8, cq = (tid & 15) * 4;
  #pragma unroll
  for (int i = 0; i < 8; ++i) {
    float bi = bias[e0 + i];
    float* po = out + ((size_t)b * DD + e0 + i) * L;
    #pragma unroll
    for (int j = 0; j < 4; ++j) {
      int l = l0 + cq + j;
      if (l < L) po[l] = acc[i][j] + bi;
    }
  }
}

// ---------------- attention: chunked LDS (26.4 KB) + 2 queries/thread ----------------
// ctx: 1 block per (b,h), thread owns queries tid and tid+256 — every K/V/mask
// LDS read amortized over 2 chains (halves LDS-pipe pressure, the R6-identified
// shared bottleneck) with 2x ILP. Online softmax carries across chunks.
__global__ __launch_bounds__(256) void k_attn2(
    const float* __restrict__ qC, const float* __restrict__ kC, const float* __restrict__ vC,
    const float* __restrict__ qQ, const float* __restrict__ kQ, const float* __restrict__ vQ,
    const float* __restrict__ cmask, const float* __restrict__ qmask,
    float* __restrict__ oC, float* __restrict__ oQ) {
  int blk = blockIdx.x;
  const float *qp, *kp, *vp, *mk; float* op; int L, b, h;
  if (blk < 512) {
    b = blk >> 3; h = blk & 7;
    qp = qC; kp = kC; vp = vC; mk = cmask; op = oC; L = NN;
  } else {
    int bb = blk - 512; b = bb >> 3; h = bb & 7;
    qp = qQ; kp = kQ; vp = vQ; mk = qmask; op = oQ; L = MM;
  }
  __shared__ float Kl[CH * KDIM];
  __shared__ float Vl[CH * KDIM];
  __shared__ float Ml[CH + 8];
  int tid = threadIdx.x;
  size_t base = ((size_t)b * DD + h * KDIM) * L;
  int i1 = tid, i2 = tid + 256;
  bool a1 = i1 < L, a2 = i2 < L;
  float q1[KDIM], q2[KDIM];
  #pragma unroll
  for (int t = 0; t < KDIM; ++t) {
    q1[t] = a1 ? qp[base + (size_t)t * L + i1] * 0.25f : 0.f;
    q2[t] = a2 ? qp[base + (size_t)t * L + i2] * 0.25f : 0.f;
  }
  float m1 = -1e30f, m2 = -1e30f, ls1 = 0.f, ls2 = 0.f;
  float acc1[KDIM], acc2[KDIM];
  #pragma unroll
  for (int t = 0; t < KDIM; ++t) { acc1[t] = 0.f; acc2[t] = 0.f; }

  for (int c0 = 0; c0 < L; c0 += CH) {
    int ch = L - c0; if (ch > CH) ch = CH;
    int chp = (ch + 7) & ~7;   // 200 or 56
    const float* kpc = kp + base + c0;
    const float* vpc = vp + base + c0;
    for (int idx = tid; idx < KDIM * ch; idx += 256) {
      int t = idx / ch, j = idx - t * ch;
      Kl[j * KDIM + t] = kpc[(size_t)t * L + j];
      Vl[j * KDIM + t] = vpc[(size_t)t * L + j];
    }
    for (int idx = tid; idx < (chp - ch) * KDIM; idx += 256) {
      int j = ch + (idx >> 4), t = idx & 15;
      Kl[j * KDIM + t] = 0.f; Vl[j * KDIM + t] = 0.f;
    }
    for (int j = tid; j < chp; j += 256)
      Ml[j] = (j < ch) ? -1e30f * (1.0f - mk[b * L + c0 + j]) : -1e30f;
    __syncthreads();
    if (a1) {
      for (int j0 = 0; j0 < chp; j0 += 8) {
        const float4* mp = (const float4*)&Ml[j0];
        float4 ma0 = mp[0], ma1 = mp[1];
        float mav[8] = {ma0.x, ma0.y, ma0.z, ma0.w, ma1.x, ma1.y, ma1.z, ma1.w};
        float s1[8], s2[8];
        #pragma unroll
        for (int jj = 0; jj < 8; ++jj) {
          const float4* kf = (const float4*)&Kl[(j0 + jj) * KDIM];
          float4 k0 = kf[0], k1 = kf[1], k2 = kf[2], k3 = kf[3];
          float d1a = q1[0] * k0.x + q1[1] * k0.y + q1[2] * k0.z + q1[3] * k0.w
                    + q1[4] * k1.x + q1[5] * k1.y + q1[6] * k1.z + q1[7] * k1.w;
          float d1b = q1[8] * k2.x + q1[9] * k2.y + q1[10] * k2.z + q1[11] * k2.w
                    + q1[12] * k3.x + q1[13] * k3.y + q1[14] * k3.z + q1[15] * k3.w;
          float d2a = q2[0] * k0.x + q2[1] * k0.y + q2[2] * k0.z + q2[3] * k0.w
                    + q2[4] * k1.x + q2[5] * k1.y + q2[6] * k1.z + q2[7] * k1.w;
          float d2b = q2[8] * k2.x + q2[9] * k2.y + q2[10] * k2.z + q2[11] * k2.w
                    + q2[12] * k3.x + q2[13] * k3.y + q2[14] * k3.z + q2[15] * k3.w;
          s1[jj] = d1a + d1b + mav[jj];
          s2[jj] = d2a + d2b + mav[jj];
        }
        float cm1 = s1[0], cm2 = s2[0];
        #pragma unroll
        for (int jj = 1; jj < 8; ++jj) { cm1 = fmaxf(cm1, s1[jj]); cm2 = fmaxf(cm2, s2[jj]); }
        if (cm1 > m1) {  // exact: skipped branch would multiply by exp(0)=1
          float sc = __expf(m1 - cm1);
          ls1 *= sc;
          #pragma unroll
          for (int t = 0; t < KDIM; ++t) acc1[t] *= sc;
          m1 = cm1;
        }
        if (cm2 > m2) {
          float sc = __expf(m2 - cm2);
          ls2 *= sc;
          #pragma unroll
          for (int t = 0; t < KDIM; ++t) acc2[t] *= sc;
          m2 = cm2;
        }
        #pragma unroll
        for (int jj = 0; jj < 8; ++jj) {
          float p1 = __expf(s1[jj] - m1);
          float p2 = __expf(s2[jj] - m2);
          ls1 += p1; ls2 += p2;
          const float4* vf = (const float4*)&Vl[(j0 + jj) * KDIM];
          float4 v0 = vf[0], v1 = vf[1], v2 = vf[2], v3 = vf[3];
          acc1[0] += p1 * v0.x;  acc1[1] += p1 * v0.y;  acc1[2] += p1 * v0.z;  acc1[3] += p1 * v0.w;
          acc1[4] += p1 * v1.x;  acc1[5] += p1 * v1.y;  acc1[6] += p1 * v1.z;  acc1[7] += p1 * v1.w;
          acc1[8] += p1 * v2.x;  acc1[9] += p1 * v2.y;  acc1[10] += p1 * v2.z; acc1[11] += p1 * v2.w;
          acc1[12] += p1 * v3.x; acc1[13] += p1 * v3.y; acc1[14] += p1 * v3.z; acc1[15] += p1 * v3.w;
          acc2[0] += p2 * v0.x;  acc2[1] += p2 * v0.y;  acc2[2] += p2 * v0.z;  acc2[3] += p2 * v0.w;
          acc2[4] += p2 * v1.x;  acc2[5] += p2 * v1.y;  acc2[6] += p2 * v1.z;  acc2[7] += p2 * v1.w;
          acc2[8] += p2 * v2.x;  acc2[9] += p2 * v2.y;  acc2[10] += p2 * v2.z; acc2[11] += p2 * v2.w;
          acc2[12] += p2 * v3.x; acc2[13] += p2 * v3.y; acc2[14] += p2 * v3.z; acc2[15] += p2 * v3.w;
        }
      }
    }
    __syncthreads();  // chunk compute done before next stage overwrites LDS
  }
  if (a1) {
    float invl = 1.0f / ls1;
    #pragma unroll
    for (int t = 0; t < KDIM; ++t)
      op[base + (size_t)t * L + i1] = acc1[t] * invl;
  }
  if (a2) {
    float invl = 1.0f / ls2;
    #pragma unroll
    for (int t = 0; t < KDIM; ++t)
      op[base + (size_t)t * L + i2] = acc2[t] * invl;
  }
}

// ---------------- fused prep: tiled transposes + dotD ----------------
__global__ void k_prep(const float* __restrict__ Cb, const float* __restrict__ Qb,
                       float* __restrict__ C2, float* __restrict__ Q2,
                       const float* __restrict__ wc, const float* __restrict__ wq,
                       float* __restrict__ cd, float* __restrict__ qd) {
  int blk = blockIdx.x, tid = threadIdx.x;
  if (blk < 3840) {
    const float* X; float* Y; int L, rem;
    if (blk < 3328) { X = Cb; Y = C2; L = NN; rem = blk; }
    else { X = Qb; Y = Q2; L = MM; rem = blk - 3328; }
    int ntl = (L + 31) / 32;
    int b = rem / (4 * ntl);
    int r2 = rem % (4 * ntl);
    int d0 = (r2 / ntl) * 32;
    int l0 = (r2 % ntl) * 32;
    __shared__ float T[32][33];
    int c = tid & 31, r8 = tid >> 5;
    const float* xb = X + (size_t)b * DD * L;
    #pragma unroll
    for (int k = 0; k < 4; ++k) {
      int r = r8 + k * 8;
      int l = l0 + c;
      T[r][c] = (l < L) ? xb[(size_t)(d0 + r) * L + l] : 0.f;
    }
    __syncthreads();
    float* yb = Y + (size_t)b * L * DD;
    #pragma unroll
    for (int k = 0; k < 4; ++k) {
      int rr = r8 + k * 8;
      int l = l0 + rr;
      if (l < L) yb[(size_t)l * DD + d0 + c] = T[c][rr];
    }
  } else if (blk < 3940) {
    int idx = (blk - 3840) * 256 + tid;
    if (idx < BB * NN) {
      int l = idx % NN, b = idx / NN;
      const float* px = Cb + (size_t)b * DD * NN + l;
      float acc = 0.f;
      for (int d = 0; d < DD; ++d) acc += px[(size_t)d * NN] * wc[d];
      cd[idx] = acc;
    }
  } else {
    int idx = (blk - 3940) * 256 + tid;
    if (idx < BB * MM) {
      int l = idx % MM, b = idx / MM;
      const float* px = Qb + (size_t)b * DD * MM + l;
      float acc = 0.f;
      for (int d = 0; d < DD; ++d) acc += px[(size_t)d * MM] * wq[d];
      qd[idx] = acc;
    }
  }
}

// ---------------- S tiled: block per (b, 64-n tile); C2*wm and Q2 in LDS ----------------
// Padded stride 132 floats kills the n-broadcast (16-way) and m (4-way) bank conflicts.
__global__ __launch_bounds__(256) void k_S2(
    const float* __restrict__ C2, const float* __restrict__ Q2,
    const float* __restrict__ cd, const float* __restrict__ qd,
    const float* __restrict__ wm, const float* __restrict__ bias,
    float* __restrict__ S) {
  int blk = blockIdx.x;            // 448 = 64 b x 7 ntiles
  int b = blk / 7, nt = blk % 7;
  int n0 = nt * 64;
  int nv = NN - n0; if (nv > 64) nv = 64;
  __shared__ float Cw[64 * 132];
  __shared__ float Ql[52 * 132];
  __shared__ float cdl[64];
  __shared__ float qdl[50];
  int tid = threadIdx.x;
  const float4* c4g = (const float4*)(C2 + (size_t)b * NN * DD);
  const float4* q4g = (const float4*)(Q2 + (size_t)b * MM * DD);
  const float4* w4 = (const float4*)wm;
  for (int i = tid; i < 64 * 32; i += 256) {
    int n = i >> 5, d4 = i & 31;
    float4 v = {0.f, 0.f, 0.f, 0.f};
    if (n < nv) {
      float4 c = c4g[(size_t)(n0 + n) * 32 + d4];
      float4 w = w4[d4];
      v.x = c.x * w.x; v.y = c.y * w.y; v.z = c.z * w.z; v.w = c.w * w.w;
    }
    *(float4*)&Cw[n * 132 + d4 * 4] = v;
  }
  for (int i = tid; i < 52 * 32; i += 256) {
    int m = i >> 5, d4 = i & 31;
    float4 v = {0.f, 0.f, 0.f, 0.f};
    if (m < MM) v = q4g[(size_t)m * 32 + d4];
    *(float4*)&Ql[m * 132 + d4 * 4] = v;
  }
  if (tid < 64) cdl[tid] = (tid < nv) ? cd[b * NN + n0 + tid] : 0.f;
  if (tid >= 64 && tid < 114) qdl[tid - 64] = qd[b * MM + (tid - 64)];
  __syncthreads();
  int n = tid >> 2, mg = tid & 3;
  int m0 = mg * 13;                 // 13,13,13,11 m's per thread
  float acc[13];
  #pragma unroll
  for (int k = 0; k < 13; ++k) acc[k] = 0.f;
  const float* cp = &Cw[n * 132];
  for (int d4 = 0; d4 < 32; ++d4) {
    float4 c = *(const float4*)&cp[d4 * 4];
    #pragma unroll
    for (int k = 0; k < 13; ++k) {
      float4 q = *(const float4*)&Ql[(m0 + k) * 132 + d4 * 4];
      acc[k] += c.x * q.x + c.y * q.y + c.z * q.z + c.w * q.w;
    }
  }
  if (n < nv) {
    float add = cdl[n] + bias[0];
    float* ps = S + ((size_t)b * NN + n0 + n) * MM + m0;
    #pragma unroll
    for (int k = 0; k < 13; ++k) {
      int m = m0 + k;
      if (m < MM) ps[k] = acc[k] + add + qdl[m];
    }
  }
}

// ---------------- merged softmaxes ----------------
__global__ void k_smax(const float* __restrict__ S, float* __restrict__ Sr,
                       float* __restrict__ Sc, const float* __restrict__ cmask,
                       const float* __restrict__ qmask) {
  int blk = blockIdx.x;
  int tid = threadIdx.x;
  if (blk < BB * MM) {
    int b = blk / MM;
    int mcol = blk % MM;
    float vals[7];
    float mx = -1e30f;
    #pragma unroll
    for (int c = 0; c < 7; ++c) {
      int n = tid + c * 64;
      float s = -1e30f;
      if (n < NN)
        s = S[((size_t)b * NN + n) * MM + mcol] - 1e30f * (1.0f - cmask[b * NN + n]);
      vals[c] = s;
      mx = fmaxf(mx, s);
    }
    #pragma unroll
    for (int off = 1; off < 64; off <<= 1) mx = fmaxf(mx, __shfl_xor(mx, off));
    float sum = 0.f;
    #pragma unroll
    for (int c = 0; c < 7; ++c) { vals[c] = __expf(vals[c] - mx); sum += vals[c]; }
    #pragma unroll
    for (int off = 1; off < 64; off <<= 1) sum += __shfl_xor(sum, off);
    float inv = 1.0f / sum;
    #pragma unroll
    for (int c = 0; c < 7; ++c) {
      int n = tid + c * 64;
      if (n < NN) Sc[((size_t)b * NN + n) * MM + mcol] = vals[c] * inv;
    }
  } else {
    int bn = blk - BB * MM;
    int b = bn / NN;
    float s = -1e30f;
    if (tid < MM)
      s = S[(size_t)bn * MM + tid] - 1e30f * (1.0f - qmask[b * MM + tid]);
    float mx = s;
    #pragma unroll
    for (int off = 1; off < 64; off <<= 1) mx = fmaxf(mx, __shfl_xor(mx, off));
    float e = (tid < MM) ? __expf(s - mx) : 0.f;
    float sum = e;
    #pragma unroll
    for (int off = 1; off < 64; off <<= 1) sum += __shfl_xor(sum, off);
    if (tid < MM) Sr[(size_t)bn * MM + tid] = e / sum;
  }
}

// ---------------- U[b,m,d] = sum_k Sc[b,k,m]*C2[b,k,d] ----------------
__global__ void k_U(const float* __restrict__ Sc, const float* __restrict__ C2,
                    float* __restrict__ U) {
  int idx = blockIdx.x * 256 + threadIdx.x;
  if (idx >= BB * MM * 32) return;
  int d4 = idx & 31;
  int rest = idx >> 5;
  int mcol = rest % MM;
  int b = rest / MM;
  const float* psc = Sc + (size_t)b * NN * MM + mcol;
  const float4* pc2 = (const float4*)(C2 + (size_t)b * NN * DD) + d4;
  float4 acc = {0.f, 0.f, 0.f, 0.f};
  #pragma unroll 4
  for (int kk = 0; kk < NN; ++kk) {
    float s = psc[(size_t)kk * MM];
    float4 c = pc2[(size_t)kk * 32];
    acc.x += s * c.x; acc.y += s * c.y; acc.z += s * c.z; acc.w += s * c.w;
  }
  ((float4*)U)[idx] = acc;
}

// ---------------- fused A/Bt + final concat; LDS-staged Q2/Uu/Sr ----------------
__global__ __launch_bounds__(256) void k_ABtF(
    const float* __restrict__ Sr, const float* __restrict__ Q2,
    const float* __restrict__ Uu, const float* __restrict__ C2,
    float* __restrict__ out) {
  int blk = blockIdx.x;
  int b = blk / 7, nt = blk % 7;
  int n0 = nt * 64;
  int nv = NN - n0; if (nv > 64) nv = 64;
  __shared__ float Ql[MM * 128];
  __shared__ float Ul[MM * 128];
  __shared__ float Sl[64 * MM];
  int tid = threadIdx.x;
  const float4* q4 = (const float4*)(Q2 + (size_t)b * MM * DD);
  const float4* u4 = (const float4*)(Uu + (size_t)b * MM * DD);
  for (int i = tid; i < MM * 32; i += 256) {
    ((float4*)Ql)[i] = q4[i];
    ((float4*)Ul)[i] = u4[i];
  }
  for (int i = tid; i < 64 * MM; i += 256) {
    int n = i / MM;
    Sl[i] = (n < nv) ? Sr[((size_t)b * NN + n0 + n) * MM + (i - n * MM)] : 0.f;
  }
  __syncthreads();
  int n = tid >> 2;
  if (n >= nv) return;
  int d04 = (tid & 3) * 8;
  float4 accA[8], accB[8];
  #pragma unroll
  for (int r = 0; r < 8; ++r) {
    accA[r] = {0.f, 0.f, 0.f, 0.f};
    accB[r] = {0.f, 0.f, 0.f, 0.f};
  }
  const float* sp = &Sl[n * MM];
  for (int m = 0; m < MM; ++m) {
    float s = sp[m];
    const float4* qp = (const float4*)&Ql[m * 128] + d04;
    const float4* up = (const float4*)&Ul[m * 128] + d04;
    #pragma unroll
    for (int r = 0; r < 8; ++r) {
      float4 q = qp[r], u = up[r];
      accA[r].x += s * q.x; accA[r].y += s * q.y; accA[r].z += s * q.z; accA[r].w += s * q.w;
      accB[r].x += s * u.x; accB[r].y += s * u.y; accB[r].z += s * u.z; accB[r].w += s * u.w;
    }
  }
  int gn = n0 + n;
  const float4* c4 = (const float4*)(C2 + ((size_t)b * NN + gn) * DD) + d04;
  float4* po = (float4*)(out + (size_t)(b * NN + gn) * 512);
  #pragma unroll
  for (int r = 0; r < 8; ++r) {
    float4 c = c4[r];
    float4 a = accA[r], bt = accB[r];
    po[d04 + r] = c;
    po[32 + d04 + r] = a;
    float4 ca = {c.x * a.x, c.y * a.y, c.z * a.z, c.w * a.w};
    po[64 + d04 + r] = ca;
    float4 cb = {c.x * bt.x, c.y * bt.y, c.z * bt.z, c.w * bt.w};
    po[96 + d04 + r] = cb;
  }
}

extern "C" void kernel_launch(void* const* d_in, const int* in_sizes, int n_in,
                              void* d_out, int out_size, void* d_ws, size_t ws_size,
                              hipStream_t stream) {
  (void)in_sizes; (void)n_in; (void)out_size; (void)ws_size;
  const float* ctx   = (const float*)d_in[0];
  const float* que   = (const float*)d_in[1];
  const float* cmask = (const float*)d_in[2];
  const float* qmask = (const float*)d_in[3];
  const float* ln_g  = (const float*)d_in[4];
  const float* ln_b  = (const float*)d_in[5];
  const float* dw_w  = (const float*)d_in[6];
  const float* dw_b  = (const float*)d_in[7];
  const float* pw_w  = (const float*)d_in[8];
  const float* pw_b  = (const float*)d_in[9];
  const float* Wq    = (const float*)d_in[10];
  const float* bq    = (const float*)d_in[11];
  const float* Wk    = (const float*)d_in[12];
  const float* bk    = (const float*)d_in[13];
  const float* Wv    = (const float*)d_in[14];
  const float* bv    = (const float*)d_in[15];
  const float* Wo    = (const float*)d_in[16];
  const float* bo    = (const float*)d_in[17];
  const float* Wfc   = (const float*)d_in[18];
  const float* bfc   = (const float*)d_in[19];
  const float* cq_wc = (const float*)d_in[20];
  const float* cq_wq = (const float*)d_in[21];
  const float* cq_wm = (const float*)d_in[22];
  const float* cq_b  = (const float*)d_in[23];
  float* out = (float*)d_out;
  float* ws = (float*)d_ws;

  float* Cb   = ws;
  float* Qb   = Cb + SZ_C;
  float* t1C  = Qb + SZ_Q;
  float* t1Q  = t1C + SZ_C;
  float* t2C  = t1Q + SZ_Q;
  float* t2Q  = t2C + SZ_C;
  float* t3C  = t2Q + SZ_Q;
  float* t3Q  = t3C + SZ_C;
  float* t4C  = t3Q + SZ_Q;
  float* t4Q  = t4C + SZ_C;
  float* mu0  = t4Q + SZ_Q;
  float* inv0 = mu0 + SSTAT;
  float* mu1  = inv0 + SSTAT;
  float* inv1 = mu1 + SSTAT;
  float* Wcan = inv1 + SSTAT;

  k_transposeW<<<(9 * 16384 + 255) / 256, 256, 0, stream>>>(pw_w, Wo, Wfc, Wq, Wk, Wv, Wcan);
  k_pestats<<<512, 256, 0, stream>>>(ctx, que, Cb, Qb, mu0, inv0);

  for (int i = 0; i < NC; ++i) {
    const float* inC = (i & 1) ? t1C : Cb;
    const float* inQ = (i & 1) ? t1Q : Qb;
    float* oC = (i & 1) ? Cb : t1C;
    float* oQ = (i & 1) ? Qb : t1Q;
    const float* mI = (i & 1) ? mu1 : mu0;
    const float* iI = (i & 1) ? inv1 : inv0;
    float* mO = (i & 1) ? mu0 : mu1;
    float* iO = (i & 1) ? inv0 : inv1;
    k_convgemm<<<512, 256, 0, stream>>>(inC, inQ, oC, oQ,
                                        Wcan + (size_t)i * 16384, pw_b + (size_t)i * DD,
                                        dw_w + (size_t)i * DD * KW, dw_b + (size_t)i * DD,
                                        mI, iI, mO, iO, ln_g, ln_b);
  }
  k_gemm_qkv<<<1536, 256, 0, stream>>>(Cb, Qb, t1C, t1Q, t2C, t2Q, t3C, t3Q,
                                       Wcan, bq, bk, bv, mu0, inv0, ln_g, ln_b);
  k_attn2<<<1024, 256, 0, stream>>>(t1C, t2C, t3C, t1Q, t2Q, t3Q, cmask, qmask, t4C, t4Q);
  k_gemm64<0, 1, 1><<<512, 256, 0, stream>>>(t4C, t4Q, Cb, Qb, Wcan + 4 * 16384, bo,
                                             mu0, inv0, mu1, inv1, ln_g, ln_b);
  k_gemm64<1, 1, 0><<<512, 256, 0, stream>>>(Cb, Qb, Cb, Qb, Wcan + 5 * 16384, bfc,
                                             mu1, inv1, mu0, inv0, ln_g, ln_b);

  // ---- context-query attention ----
  float* C2  = t1C;
  float* Q2  = t1Q;
  float* S   = t2C;
  float* Sr  = t2C + 1638400;
  float* Scb = t3C;
  float* Uu  = t2Q;
  float* cd  = t3Q;
  float* qd  = t4Q;

  k_prep<<<3953, 256, 0, stream>>>(Cb, Qb, C2, Q2, cq_wc, cq_wq, cd, qd);
  k_S2<<<448, 256, 0, stream>>>(C2, Q2, cd, qd, cq_wm, cq_b, S);
  k_smax<<<BB * MM + BB * NN, 64, 0, stream>>>(S, Sr, Scb, cmask, qmask);
  k_U<<<(BB * MM * 32 + 255) / 256, 256, 0, stream>>>(Scb, C2, Uu);
  k_ABtF<<<448, 256, 0, stream>>>(Sr, Q2, Uu, C2, out);
}

// Round 8
// 644.227 us; speedup vs baseline: 1.1400x; 1.1400x over previous
//
#include <hip/hip_runtime.h>
#include <math.h>

#define BB 64
#define DD 128
#define NN 400
#define MM 50
#define HH 8
#define KDIM 16
#define NC 4
#define KW 7

#define SZ_C (BB * DD * NN)   // 3,276,800
#define SZ_Q (BB * DD * MM)   //   409,600
#define SSTAT (BB * NN + BB * MM)  // 28,800; q stats at offset BB*NN

// ---------------- canonical weight transpose: Wcan[m][d][e] ----------------
__global__ void k_transposeW(const float* __restrict__ pw_w, const float* __restrict__ Wo,
                             const float* __restrict__ Wfc, const float* __restrict__ Wq,
                             const float* __restrict__ Wk, const float* __restrict__ Wv,
                             float* __restrict__ Wcan) {
  int idx = blockIdx.x * 256 + threadIdx.x;
  if (idx >= 9 * 16384) return;
  int m = idx >> 14;
  int r = idx & 16383;
  int d = r >> 7, e = r & 127;
  float v;
  if (m < 4) v = pw_w[m * 16384 + e * 128 + d];
  else if (m == 4) v = Wo[d * 128 + e];
  else if (m == 5) v = Wfc[e * 128 + d];
  else {
    const float* W = (m == 6) ? Wq : (m == 7) ? Wk : Wv;
    v = W[((e >> 4) * 128 + d) * 16 + (e & 15)];
  }
  Wcan[idx] = v;
}

// ---------------- fused PE add + LN stats ----------------
__global__ void k_pestats(const float* __restrict__ xC, const float* __restrict__ xQ,
                          float* __restrict__ yC, float* __restrict__ yQ,
                          float* __restrict__ mu, float* __restrict__ inv) {
  int blk = blockIdx.x;
  const float* x; float* y; int L, l0, b, soff;
  if (blk < 448) { b = blk / 7; l0 = (blk % 7) * 64; x = xC; y = yC; L = NN; soff = 0; }
  else { b = blk - 448; l0 = 0; x = xQ; y = yQ; L = MM; soff = BB * NN; }
  int tid = threadIdx.x;
  int ll = tid & 63;
  int dq = tid >> 6;
  int l = l0 + ll;
  __shared__ float s_sum[4][64], s_sq[4][64];
  float sum = 0.f, sq = 0.f;
  if (l < L) {
    const float* px = x + (size_t)b * DD * L + l;
    float* py = y + (size_t)b * DD * L + l;
    for (int d = dq * 32; d < dq * 32 + 32; ++d) {
      int de = d & ~1;
      float freq = __expf((float)de * (-9.210340371976184f / 128.0f));
      float ph = (d & 1) ? 1.5707963267948966f : 0.0f;
      float v = px[(size_t)d * L] + sinf((float)l * freq + ph);
      py[(size_t)d * L] = v;
      sum += v; sq += v * v;
    }
  }
  s_sum[dq][ll] = sum; s_sq[dq][ll] = sq;
  __syncthreads();
  if (dq == 0 && l < L) {
    float ts = s_sum[0][ll] + s_sum[1][ll] + s_sum[2][ll] + s_sum[3][ll];
    float tq = s_sq[0][ll] + s_sq[1][ll] + s_sq[2][ll] + s_sq[3][ll];
    float m = ts * (1.0f / 128.0f);
    float var = (tq - 128.0f * m * m) * (1.0f / 127.0f);
    float sd = sqrtf(fmaxf(var, 0.f));
    mu[soff + b * L + l] = m;
    inv[soff + b * L + l] = 1.0f / (sd + 1e-6f);
  }
}

// ---------------- fused conv layer, 64-col tiles (512 blocks = 2/CU) ----------------
__global__ __launch_bounds__(256, 2) void k_convgemm(
    const float* __restrict__ xC, const float* __restrict__ xQ,
    float* __restrict__ outC, float* __restrict__ outQ,
    const float* __restrict__ Wc, const float* __restrict__ pwb,
    const float* __restrict__ dww, const float* __restrict__ dwb,
    const float* __restrict__ muI, const float* __restrict__ invI,
    float* __restrict__ muO, float* __restrict__ invO,
    const float* __restrict__ g, const float* __restrict__ beta) {
  int blk = blockIdx.x;
  int b = blk >> 3, tile = blk & 7;
  const float* x; float* out; int L, l0, soff;
  if (tile < 7) { x = xC; out = outC; L = NN; l0 = tile * 64; soff = 0; }
  else { x = xQ; out = outQ; L = MM; l0 = 0; soff = BB * NN; }
  __shared__ float Wl[32 * 128];
  __shared__ float Xl[32 * 64];
  __shared__ float Sm[70], Si[70];   // stats halo [l0-3, l0+67)
  int tid = threadIdx.x;
  const float* xb = x + (size_t)b * DD * L;
  for (int t = tid; t < 70; t += 256) {
    int gl = l0 + t - 3;
    bool ok = (gl >= 0 && gl < L);
    Sm[t] = ok ? muI[soff + b * L + gl] : 0.f;
    Si[t] = ok ? invI[soff + b * L + gl] : 0.f;
  }
  float acc[8][4];
  #pragma unroll
  for (int i = 0; i < 8; ++i)
    #pragma unroll
    for (int j = 0; j < 4; ++j) acc[i][j] = 0.f;
  __syncthreads();
  for (int kc = 0; kc < 4; ++kc) {
    int d0 = kc * 32;
    #pragma unroll
    for (int i = 0; i < 4; ++i) {
      int idx = i * 256 + tid;
      ((float4*)Wl)[idx] = ((const float4*)Wc)[(size_t)d0 * 32 + idx];
    }
    #pragma unroll
    for (int r = 0; r < 2; ++r) {
      int k = r * 16 + (tid >> 4);
      int d = d0 + k;
      int c0 = (tid & 15) * 4;
      const float* xrow = xb + (size_t)d * L;
      float gd = g[d], bd = beta[d];
      float wv[7];
      #pragma unroll
      for (int u = 0; u < 7; ++u) wv[u] = dww[d * 7 + u];
      float dbv = dwb[d];
      float xw[10];
      int gbase = l0 + c0 - 3;
      if (gbase >= 1 && gbase + 11 <= L && (((unsigned)(d * L + gbase - 1)) & 3u) == 0u) {
        const float4* p = (const float4*)&xrow[gbase - 1];
        float4 A = p[0], Bv = p[1], Cv = p[2];
        float xr[12] = {A.x, A.y, A.z, A.w, Bv.x, Bv.y, Bv.z, Bv.w, Cv.x, Cv.y, Cv.z, Cv.w};
        #pragma unroll
        for (int s = 0; s < 10; ++s)
          xw[s] = gd * (xr[s + 1] - Sm[c0 + s]) * Si[c0 + s] + bd;
      } else {
        #pragma unroll
        for (int s = 0; s < 10; ++s) {
          int gl = gbase + s;
          float v = 0.f;
          if (gl >= 0 && gl < L)
            v = gd * (xrow[gl] - Sm[c0 + s]) * Si[c0 + s] + bd;
          xw[s] = v;
        }
      }
      float4 o;
      o.x = dbv; o.y = dbv; o.z = dbv; o.w = dbv;
      #pragma unroll
      for (int u = 0; u < 7; ++u) {
        o.x += wv[u] * xw[u];
        o.y += wv[u] * xw[u + 1];
        o.z += wv[u] * xw[u + 2];
        o.w += wv[u] * xw[u + 3];
      }
      *(float4*)&Xl[k * 64 + c0] = o;
    }
    __syncthreads();
    int e0 = (tid >> 4) * 8, cq = (tid & 15) * 4;
    for (int k = 0; k < 32; ++k) {
      const float4* wp = (const float4*)&Wl[k * 128 + e0];
      float4 w0 = wp[0], w1 = wp[1];
      float4 xv = *(const float4*)&Xl[k * 64 + cq];
      float we[8] = {w0.x, w0.y, w0.z, w0.w, w1.x, w1.y, w1.z, w1.w};
      float xe[4] = {xv.x, xv.y, xv.z, xv.w};
      #pragma unroll
      for (int i = 0; i < 8; ++i)
        #pragma unroll
        for (int j = 0; j < 4; ++j) acc[i][j] += we[i] * xe[j];
    }
    __syncthreads();
  }
  int e0 = (tid >> 4) * 8, cq = (tid & 15) * 4;
  float ssum[4], ssq[4];
  #pragma unroll
  for (int j = 0; j < 4; ++j) { ssum[j] = 0.f; ssq[j] = 0.f; }
  #pragma unroll
  for (int i = 0; i < 8; ++i) {
    float bi = pwb[e0 + i];
    float* po = out + ((size_t)b * DD + e0 + i) * L;
    const float* pr = xb + (size_t)(e0 + i) * L;
    #pragma unroll
    for (int j = 0; j < 4; ++j) {
      int l = l0 + cq + j;
      if (l < L) {
        float v = fmaxf(acc[i][j] + bi, 0.f) + pr[l];
        po[l] = v;
        ssum[j] += v; ssq[j] += v * v;
      }
    }
  }
  int grp = tid >> 4;
  #pragma unroll
  for (int j = 0; j < 4; ++j) {
    Xl[grp * 64 + cq + j] = ssum[j];
    Wl[grp * 64 + cq + j] = ssq[j];
  }
  __syncthreads();
  if (tid < 64) {
    int l = l0 + tid;
    if (l < L) {
      float ts = 0.f, tq = 0.f;
      #pragma unroll
      for (int gg = 0; gg < 16; ++gg) { ts += Xl[gg * 64 + tid]; tq += Wl[gg * 64 + tid]; }
      float m = ts * (1.0f / 128.0f);
      float var = (tq - 128.0f * m * m) * (1.0f / 127.0f);
      float sd = sqrtf(fmaxf(var, 0.f));
      muO[soff + b * L + l] = m;
      invO[soff + b * L + l] = 1.0f / (sd + 1e-6f);
    }
  }
}

// ---------------- 128x64 GEMM tiles, 512 blocks ----------------
template <int LNF, int ACT, int STATS>
__global__ __launch_bounds__(256) void k_gemm64(
    const float* __restrict__ xC, const float* __restrict__ xQ,
    float* __restrict__ outC, float* __restrict__ outQ,
    const float* __restrict__ Wc, const float* __restrict__ bias,
    const float* __restrict__ mu, const float* __restrict__ inv,
    float* __restrict__ muO, float* __restrict__ invO,
    const float* __restrict__ g, const float* __restrict__ beta) {
  int blk = blockIdx.x;
  int b = blk >> 3, tile = blk & 7;
  const float* x; float* out; int L, l0, soff;
  if (tile < 7) { x = xC; out = outC; L = NN; l0 = tile * 64; soff = 0; }
  else { x = xQ; out = outQ; L = MM; l0 = 0; soff = BB * NN; }
  __shared__ float Wl[32 * 128];
  __shared__ float Xl[32 * 64];
  int tid = threadIdx.x;
  float acc[8][4];
  #pragma unroll
  for (int i = 0; i < 8; ++i)
    #pragma unroll
    for (int j = 0; j < 4; ++j) acc[i][j] = 0.f;
  const float* xb = x + (size_t)b * DD * L;
  const float* pmu = mu + soff + b * L;
  const float* pin = inv + soff + b * L;
  for (int kc = 0; kc < 4; ++kc) {
    int d0 = kc * 32;
    #pragma unroll
    for (int i = 0; i < 4; ++i) {
      int idx = i * 256 + tid;
      ((float4*)Wl)[idx] = ((const float4*)Wc)[(size_t)d0 * 32 + idx];
    }
    #pragma unroll
    for (int t = 0; t < 8; ++t) {
      int idx = t * 256 + tid;
      int k = idx >> 6, l = idx & 63;
      float v = 0.f;
      int gl = l0 + l;
      if (gl < L) {
        v = xb[(size_t)(d0 + k) * L + gl];
        if (LNF) v = g[d0 + k] * (v - pmu[gl]) * pin[gl] + beta[d0 + k];
      }
      Xl[idx] = v;
    }
    __syncthreads();
    int e0 = (tid >> 4) * 8, cq = (tid & 15) * 4;
    for (int k = 0; k < 32; ++k) {
      const float4* wp = (const float4*)&Wl[k * 128 + e0];
      float4 w0 = wp[0], w1 = wp[1];
      float4 xv = *(const float4*)&Xl[k * 64 + cq];
      float we[8] = {w0.x, w0.y, w0.z, w0.w, w1.x, w1.y, w1.z, w1.w};
      float xe[4] = {xv.x, xv.y, xv.z, xv.w};
      #pragma unroll
      for (int i = 0; i < 8; ++i)
        #pragma unroll
        for (int j = 0; j < 4; ++j) acc[i][j] += we[i] * xe[j];
    }
    __syncthreads();
  }
  int e0 = (tid >> 4) * 8, cq = (tid & 15) * 4;
  float ssum[4], ssq[4];
  #pragma unroll
  for (int j = 0; j < 4; ++j) { ssum[j] = 0.f; ssq[j] = 0.f; }
  #pragma unroll
  for (int i = 0; i < 8; ++i) {
    float bi = bias[e0 + i];
    float* po = out + ((size_t)b * DD + e0 + i) * L;
    #pragma unroll
    for (int j = 0; j < 4; ++j) {
      int l = l0 + cq + j;
      if (l < L) {
        float v = acc[i][j] + bi;
        if (ACT != 0) v += po[l];
        po[l] = v;
        if (STATS) { ssum[j] += v; ssq[j] += v * v; }
      }
    }
  }
  if (STATS) {
    int grp = tid >> 4;
    #pragma unroll
    for (int j = 0; j < 4; ++j) {
      Xl[grp * 64 + cq + j] = ssum[j];
      Wl[grp * 64 + cq + j] = ssq[j];
    }
    __syncthreads();
    if (tid < 64) {
      int l = l0 + tid;
      if (l < L) {
        float ts = 0.f, tq = 0.f;
        #pragma unroll
        for (int gg = 0; gg < 16; ++gg) { ts += Xl[gg * 64 + tid]; tq += Wl[gg * 64 + tid]; }
        float m = ts * (1.0f / 128.0f);
        float var = (tq - 128.0f * m * m) * (1.0f / 127.0f);
        float sd = sqrtf(fmaxf(var, 0.f));
        muO[soff + b * L + l] = m;
        invO[soff + b * L + l] = 1.0f / (sd + 1e-6f);
      }
    }
  }
}

// ---------------- fused QKV GEMM: 3 x 512 blocks ----------------
__global__ __launch_bounds__(256) void k_gemm_qkv(
    const float* __restrict__ xC, const float* __restrict__ xQ,
    float* __restrict__ o1C, float* __restrict__ o1Q,
    float* __restrict__ o2C, float* __restrict__ o2Q,
    float* __restrict__ o3C, float* __restrict__ o3Q,
    const float* __restrict__ Wcan,
    const float* __restrict__ bq, const float* __restrict__ bk, const float* __restrict__ bv,
    const float* __restrict__ mu, const float* __restrict__ inv,
    const float* __restrict__ g, const float* __restrict__ beta) {
  int blk0 = blockIdx.x;
  int grp = blk0 >> 9;
  int blk = blk0 & 511;
  const float* Wc = Wcan + (size_t)(6 + grp) * 16384;
  const float* bias = (grp == 0) ? bq : (grp == 1) ? bk : bv;
  float* oC = (grp == 0) ? o1C : (grp == 1) ? o2C : o3C;
  float* oQ = (grp == 0) ? o1Q : (grp == 1) ? o2Q : o3Q;
  int b = blk >> 3, tile = blk & 7;
  const float* x; float* out; int L, l0, soff;
  if (tile < 7) { x = xC; out = oC; L = NN; l0 = tile * 64; soff = 0; }
  else { x = xQ; out = oQ; L = MM; l0 = 0; soff = BB * NN; }
  __shared__ float Wl[32 * 128];
  __shared__ float Xl[32 * 64];
  int tid = threadIdx.x;
  float acc[8][4];
  #pragma unroll
  for (int i = 0; i < 8; ++i)
    #pragma unroll
    for (int j = 0; j < 4; ++j) acc[i][j] = 0.f;
  const float* xb = x + (size_t)b * DD * L;
  const float* pmu = mu + soff + b * L;
  const float* pin = inv + soff + b * L;
  for (int kc = 0; kc < 4; ++kc) {
    int d0 = kc * 32;
    #pragma unroll
    for (int i = 0; i < 4; ++i) {
      int idx = i * 256 + tid;
      ((float4*)Wl)[idx] = ((const float4*)Wc)[(size_t)d0 * 32 + idx];
    }
    #pragma unroll
    for (int t = 0; t < 8; ++t) {
      int idx = t * 256 + tid;
      int k = idx >> 6, l = idx & 63;
      float v = 0.f;
      int gl = l0 + l;
      if (gl < L) {
        v = xb[(size_t)(d0 + k) * L + gl];
        v = g[d0 + k] * (v - pmu[gl]) * pin[gl] + beta[d0 + k];
      }
      Xl[idx] = v;
    }
    __syncthreads();
    int e0 = (tid >> 4) * 8, cq = (tid & 15) * 4;
    for (int k = 0; k < 32; ++k) {
      const float4* wp = (const float4*)&Wl[k * 128 + e0];
      float4 w0 = wp[0], w1 = wp[1];
      float4 xv = *(const float4*)&Xl[k * 64 + cq];
      float we[8] = {w0.x, w0.y, w0.z, w0.w, w1.x, w1.y, w1.z, w1.w};
      float xe[4] = {xv.x, xv.y, xv.z, xv.w};
      #pragma unroll
      for (int i = 0; i < 8; ++i)
        #pragma unroll
        for (int j = 0; j < 4; ++j) acc[i][j] += we[i] * xe[j];
    }
    __syncthreads();
  }
  int e0 = (tid >> 4) * 8, cq = (tid & 15) * 4;
  #pragma unroll
  for (int i = 0; i < 8; ++i) {
    float bi = bias[e0 + i];
    float* po = out + ((size_t)b * DD + e0 + i) * L;
    #pragma unroll
    for (int j = 0; j < 4; ++j) {
      int l = l0 + cq + j;
      if (l < L) po[l] = acc[i][j] + bi;
    }
  }
}

// ---------------- attention (R5 champion: 1q/thread, ctx split, 53 KB LDS) ----------------
// ctx: 2 blocks per (b,h) splitting the 400 queries [0,256)/[256,400);
// 1 query per thread, inactive threads exit right after staging (no later syncs).
// Scalar-fp32 floor verified across 4 structures (R1/R5/R6/R7): ~164 us.
__global__ __launch_bounds__(256) void k_attn2(
    const float* __restrict__ qC, const float* __restrict__ kC, const float* __restrict__ vC,
    const float* __restrict__ qQ, const float* __restrict__ kQ, const float* __restrict__ vQ,
    const float* __restrict__ cmask, const float* __restrict__ qmask,
    float* __restrict__ oC, float* __restrict__ oQ) {
  int blk = blockIdx.x;
  const float *qp, *kp, *vp, *mk; float* op; int L, b, h, q0, qcnt;
  if (blk < 1024) {
    b = blk >> 4; h = (blk >> 1) & 7; int half = blk & 1;
    qp = qC; kp = kC; vp = vC; mk = cmask; op = oC; L = NN;
    q0 = half * 256; qcnt = half ? (NN - 256) : 256;
  } else {
    int bb = blk - 1024; b = bb >> 3; h = bb & 7;
    qp = qQ; kp = kQ; vp = vQ; mk = qmask; op = oQ; L = MM;
    q0 = 0; qcnt = MM;
  }
  __shared__ float Kl[NN * KDIM];
  __shared__ float Vl[NN * KDIM];
  __shared__ float Ml[NN];
  int tid = threadIdx.x;
  size_t base = ((size_t)b * DD + h * KDIM) * L;
  int KP = (L + 7) & ~7;
  for (int idx = tid; idx < KDIM * L; idx += 256) {
    int t = idx / L, j = idx - t * L;
    Kl[j * KDIM + t] = kp[base + (size_t)t * L + j];
    Vl[j * KDIM + t] = vp[base + (size_t)t * L + j];
  }
  for (int idx = tid; idx < (KP - L) * KDIM; idx += 256) {
    int j = L + (idx >> 4), t = idx & 15;
    Kl[j * KDIM + t] = 0.f; Vl[j * KDIM + t] = 0.f;
  }
  for (int j = tid; j < KP; j += 256)
    Ml[j] = (j < L) ? -1e30f * (1.0f - mk[b * L + j]) : -1e30f;
  __syncthreads();
  if (tid >= qcnt) return;

  int i = q0 + tid;
  float q[KDIM];
  #pragma unroll
  for (int t = 0; t < KDIM; ++t) q[t] = qp[base + (size_t)t * L + i] * 0.25f;
  float m = -1e30f, ls = 0.f;
  float acc[KDIM];
  #pragma unroll
  for (int t = 0; t < KDIM; ++t) acc[t] = 0.f;
  for (int j0 = 0; j0 < KP; j0 += 8) {
    const float4* mp = (const float4*)&Ml[j0];
    float4 ma0 = mp[0], ma1 = mp[1];
    float mav[8] = {ma0.x, ma0.y, ma0.z, ma0.w, ma1.x, ma1.y, ma1.z, ma1.w};
    float s[8];
    #pragma unroll
    for (int jj = 0; jj < 8; ++jj) {
      const float4* kf = (const float4*)&Kl[(j0 + jj) * KDIM];
      float4 k0 = kf[0], k1 = kf[1], k2 = kf[2], k3 = kf[3];
      float da = q[0] * k0.x + q[1] * k0.y + q[2] * k0.z + q[3] * k0.w
               + q[4] * k1.x + q[5] * k1.y + q[6] * k1.z + q[7] * k1.w;
      float db = q[8] * k2.x + q[9] * k2.y + q[10] * k2.z + q[11] * k2.w
               + q[12] * k3.x + q[13] * k3.y + q[14] * k3.z + q[15] * k3.w;
      s[jj] = da + db + mav[jj];
    }
    float cm = s[0];
    #pragma unroll
    for (int jj = 1; jj < 8; ++jj) cm = fmaxf(cm, s[jj]);
    if (cm > m) {  // exact: skipped branch would multiply by exp(0)=1
      float sc = __expf(m - cm);
      ls *= sc;
      #pragma unroll
      for (int t = 0; t < KDIM; ++t) acc[t] *= sc;
      m = cm;
    }
    #pragma unroll
    for (int jj = 0; jj < 8; ++jj) {
      float p = __expf(s[jj] - m);
      ls += p;
      const float4* vf = (const float4*)&Vl[(j0 + jj) * KDIM];
      float4 v0 = vf[0], v1 = vf[1], v2 = vf[2], v3 = vf[3];
      acc[0] += p * v0.x;  acc[1] += p * v0.y;  acc[2] += p * v0.z;  acc[3] += p * v0.w;
      acc[4] += p * v1.x;  acc[5] += p * v1.y;  acc[6] += p * v1.z;  acc[7] += p * v1.w;
      acc[8] += p * v2.x;  acc[9] += p * v2.y;  acc[10] += p * v2.z; acc[11] += p * v2.w;
      acc[12] += p * v3.x; acc[13] += p * v3.y; acc[14] += p * v3.z; acc[15] += p * v3.w;
    }
  }
  float invl = 1.0f / ls;
  #pragma unroll
  for (int t = 0; t < KDIM; ++t)
    op[base + (size_t)t * L + i] = acc[t] * invl;
}

// ---------------- fused prep: tiled transposes + dotD ----------------
__global__ void k_prep(const float* __restrict__ Cb, const float* __restrict__ Qb,
                       float* __restrict__ C2, float* __restrict__ Q2,
                       const float* __restrict__ wc, const float* __restrict__ wq,
                       float* __restrict__ cd, float* __restrict__ qd) {
  int blk = blockIdx.x, tid = threadIdx.x;
  if (blk < 3840) {
    const float* X; float* Y; int L, rem;
    if (blk < 3328) { X = Cb; Y = C2; L = NN; rem = blk; }
    else { X = Qb; Y = Q2; L = MM; rem = blk - 3328; }
    int ntl = (L + 31) / 32;
    int b = rem / (4 * ntl);
    int r2 = rem % (4 * ntl);
    int d0 = (r2 / ntl) * 32;
    int l0 = (r2 % ntl) * 32;
    __shared__ float T[32][33];
    int c = tid & 31, r8 = tid >> 5;
    const float* xb = X + (size_t)b * DD * L;
    #pragma unroll
    for (int k = 0; k < 4; ++k) {
      int r = r8 + k * 8;
      int l = l0 + c;
      T[r][c] = (l < L) ? xb[(size_t)(d0 + r) * L + l] : 0.f;
    }
    __syncthreads();
    float* yb = Y + (size_t)b * L * DD;
    #pragma unroll
    for (int k = 0; k < 4; ++k) {
      int rr = r8 + k * 8;
      int l = l0 + rr;
      if (l < L) yb[(size_t)l * DD + d0 + c] = T[c][rr];
    }
  } else if (blk < 3940) {
    int idx = (blk - 3840) * 256 + tid;
    if (idx < BB * NN) {
      int l = idx % NN, b = idx / NN;
      const float* px = Cb + (size_t)b * DD * NN + l;
      float acc = 0.f;
      for (int d = 0; d < DD; ++d) acc += px[(size_t)d * NN] * wc[d];
      cd[idx] = acc;
    }
  } else {
    int idx = (blk - 3940) * 256 + tid;
    if (idx < BB * MM) {
      int l = idx % MM, b = idx / MM;
      const float* px = Qb + (size_t)b * DD * MM + l;
      float acc = 0.f;
      for (int d = 0; d < DD; ++d) acc += px[(size_t)d * MM] * wq[d];
      qd[idx] = acc;
    }
  }
}

// ---------------- S tiled: block per (b, 64-n tile); C2*wm and Q2 in LDS ----------------
__global__ __launch_bounds__(256) void k_S2(
    const float* __restrict__ C2, const float* __restrict__ Q2,
    const float* __restrict__ cd, const float* __restrict__ qd,
    const float* __restrict__ wm, const float* __restrict__ bias,
    float* __restrict__ S) {
  int blk = blockIdx.x;            // 448 = 64 b x 7 ntiles
  int b = blk / 7, nt = blk % 7;
  int n0 = nt * 64;
  int nv = NN - n0; if (nv > 64) nv = 64;
  __shared__ float Cw[64 * 132];
  __shared__ float Ql[52 * 132];
  __shared__ float cdl[64];
  __shared__ float qdl[50];
  int tid = threadIdx.x;
  const float4* c4g = (const float4*)(C2 + (size_t)b * NN * DD);
  const float4* q4g = (const float4*)(Q2 + (size_t)b * MM * DD);
  const float4* w4 = (const float4*)wm;
  for (int i = tid; i < 64 * 32; i += 256) {
    int n = i >> 5, d4 = i & 31;
    float4 v = {0.f, 0.f, 0.f, 0.f};
    if (n < nv) {
      float4 c = c4g[(size_t)(n0 + n) * 32 + d4];
      float4 w = w4[d4];
      v.x = c.x * w.x; v.y = c.y * w.y; v.z = c.z * w.z; v.w = c.w * w.w;
    }
    *(float4*)&Cw[n * 132 + d4 * 4] = v;
  }
  for (int i = tid; i < 52 * 32; i += 256) {
    int m = i >> 5, d4 = i & 31;
    float4 v = {0.f, 0.f, 0.f, 0.f};
    if (m < MM) v = q4g[(size_t)m * 32 + d4];
    *(float4*)&Ql[m * 132 + d4 * 4] = v;
  }
  if (tid < 64) cdl[tid] = (tid < nv) ? cd[b * NN + n0 + tid] : 0.f;
  if (tid >= 64 && tid < 114) qdl[tid - 64] = qd[b * MM + (tid - 64)];
  __syncthreads();
  int n = tid >> 2, mg = tid & 3;
  int m0 = mg * 13;                 // 13,13,13,11 m's per thread
  float acc[13];
  #pragma unroll
  for (int k = 0; k < 13; ++k) acc[k] = 0.f;
  const float* cp = &Cw[n * 132];
  for (int d4 = 0; d4 < 32; ++d4) {
    float4 c = *(const float4*)&cp[d4 * 4];
    #pragma unroll
    for (int k = 0; k < 13; ++k) {
      float4 q = *(const float4*)&Ql[(m0 + k) * 132 + d4 * 4];
      acc[k] += c.x * q.x + c.y * q.y + c.z * q.z + c.w * q.w;
    }
  }
  if (n < nv) {
    float add = cdl[n] + bias[0];
    float* ps = S + ((size_t)b * NN + n0 + n) * MM + m0;
    #pragma unroll
    for (int k = 0; k < 13; ++k) {
      int m = m0 + k;
      if (m < MM) ps[k] = acc[k] + add + qdl[m];
    }
  }
}

// ---------------- merged softmaxes ----------------
__global__ void k_smax(const float* __restrict__ S, float* __restrict__ Sr,
                       float* __restrict__ Sc, const float* __restrict__ cmask,
                       const float* __restrict__ qmask) {
  int blk = blockIdx.x;
  int tid = threadIdx.x;
  if (blk < BB * MM) {
    int b = blk / MM;
    int mcol = blk % MM;
    float vals[7];
    float mx = -1e30f;
    #pragma unroll
    for (int c = 0; c < 7; ++c) {
      int n = tid + c * 64;
      float s = -1e30f;
      if (n < NN)
        s = S[((size_t)b * NN + n) * MM + mcol] - 1e30f * (1.0f - cmask[b * NN + n]);
      vals[c] = s;
      mx = fmaxf(mx, s);
    }
    #pragma unroll
    for (int off = 1; off < 64; off <<= 1) mx = fmaxf(mx, __shfl_xor(mx, off));
    float sum = 0.f;
    #pragma unroll
    for (int c = 0; c < 7; ++c) { vals[c] = __expf(vals[c] - mx); sum += vals[c]; }
    #pragma unroll
    for (int off = 1; off < 64; off <<= 1) sum += __shfl_xor(sum, off);
    float inv = 1.0f / sum;
    #pragma unroll
    for (int c = 0; c < 7; ++c) {
      int n = tid + c * 64;
      if (n < NN) Sc[((size_t)b * NN + n) * MM + mcol] = vals[c] * inv;
    }
  } else {
    int bn = blk - BB * MM;
    int b = bn / NN;
    float s = -1e30f;
    if (tid < MM)
      s = S[(size_t)bn * MM + tid] - 1e30f * (1.0f - qmask[b * MM + tid]);
    float mx = s;
    #pragma unroll
    for (int off = 1; off < 64; off <<= 1) mx = fmaxf(mx, __shfl_xor(mx, off));
    float e = (tid < MM) ? __expf(s - mx) : 0.f;
    float sum = e;
    #pragma unroll
    for (int off = 1; off < 64; off <<= 1) sum += __shfl_xor(sum, off);
    if (tid < MM) Sr[(size_t)bn * MM + tid] = e / sum;
  }
}

// ---------------- U[b,m,d] = sum_k Sc[b,k,m]*C2[b,k,d] ----------------
__global__ void k_U(const float* __restrict__ Sc, const float* __restrict__ C2,
                    float* __restrict__ U) {
  int idx = blockIdx.x * 256 + threadIdx.x;
  if (idx >= BB * MM * 32) return;
  int d4 = idx & 31;
  int rest = idx >> 5;
  int mcol = rest % MM;
  int b = rest / MM;
  const float* psc = Sc + (size_t)b * NN * MM + mcol;
  const float4* pc2 = (const float4*)(C2 + (size_t)b * NN * DD) + d4;
  float4 acc = {0.f, 0.f, 0.f, 0.f};
  #pragma unroll 4
  for (int kk = 0; kk < NN; ++kk) {
    float s = psc[(size_t)kk * MM];
    float4 c = pc2[(size_t)kk * 32];
    acc.x += s * c.x; acc.y += s * c.y; acc.z += s * c.z; acc.w += s * c.w;
  }
  ((float4*)U)[idx] = acc;
}

// ---------------- fused A/Bt + final concat; LDS-staged Q2/Uu/Sr ----------------
__global__ __launch_bounds__(256) void k_ABtF(
    const float* __restrict__ Sr, const float* __restrict__ Q2,
    const float* __restrict__ Uu, const float* __restrict__ C2,
    float* __restrict__ out) {
  int blk = blockIdx.x;
  int b = blk / 7, nt = blk % 7;
  int n0 = nt * 64;
  int nv = NN - n0; if (nv > 64) nv = 64;
  __shared__ float Ql[MM * 128];
  __shared__ float Ul[MM * 128];
  __shared__ float Sl[64 * MM];
  int tid = threadIdx.x;
  const float4* q4 = (const float4*)(Q2 + (size_t)b * MM * DD);
  const float4* u4 = (const float4*)(Uu + (size_t)b * MM * DD);
  for (int i = tid; i < MM * 32; i += 256) {
    ((float4*)Ql)[i] = q4[i];
    ((float4*)Ul)[i] = u4[i];
  }
  for (int i = tid; i < 64 * MM; i += 256) {
    int n = i / MM;
    Sl[i] = (n < nv) ? Sr[((size_t)b * NN + n0 + n) * MM + (i - n * MM)] : 0.f;
  }
  __syncthreads();
  int n = tid >> 2;
  if (n >= nv) return;
  int d04 = (tid & 3) * 8;
  float4 accA[8], accB[8];
  #pragma unroll
  for (int r = 0; r < 8; ++r) {
    accA[r] = {0.f, 0.f, 0.f, 0.f};
    accB[r] = {0.f, 0.f, 0.f, 0.f};
  }
  const float* sp = &Sl[n * MM];
  for (int m = 0; m < MM; ++m) {
    float s = sp[m];
    const float4* qp = (const float4*)&Ql[m * 128] + d04;
    const float4* up = (const float4*)&Ul[m * 128] + d04;
    #pragma unroll
    for (int r = 0; r < 8; ++r) {
      float4 q = qp[r], u = up[r];
      accA[r].x += s * q.x; accA[r].y += s * q.y; accA[r].z += s * q.z; accA[r].w += s * q.w;
      accB[r].x += s * u.x; accB[r].y += s * u.y; accB[r].z += s * u.z; accB[r].w += s * u.w;
    }
  }
  int gn = n0 + n;
  const float4* c4 = (const float4*)(C2 + ((size_t)b * NN + gn) * DD) + d04;
  float4* po = (float4*)(out + (size_t)(b * NN + gn) * 512);
  #pragma unroll
  for (int r = 0; r < 8; ++r) {
    float4 c = c4[r];
    float4 a = accA[r], bt = accB[r];
    po[d04 + r] = c;
    po[32 + d04 + r] = a;
    float4 ca = {c.x * a.x, c.y * a.y, c.z * a.z, c.w * a.w};
    po[64 + d04 + r] = ca;
    float4 cb = {c.x * bt.x, c.y * bt.y, c.z * bt.z, c.w * bt.w};
    po[96 + d04 + r] = cb;
  }
}

extern "C" void kernel_launch(void* const* d_in, const int* in_sizes, int n_in,
                              void* d_out, int out_size, void* d_ws, size_t ws_size,
                              hipStream_t stream) {
  (void)in_sizes; (void)n_in; (void)out_size; (void)ws_size;
  const float* ctx   = (const float*)d_in[0];
  const float* que   = (const float*)d_in[1];
  const float* cmask = (const float*)d_in[2];
  const float* qmask = (const float*)d_in[3];
  const float* ln_g  = (const float*)d_in[4];
  const float* ln_b  = (const float*)d_in[5];
  const float* dw_w  = (const float*)d_in[6];
  const float* dw_b  = (const float*)d_in[7];
  const float* pw_w  = (const float*)d_in[8];
  const float* pw_b  = (const float*)d_in[9];
  const float* Wq    = (const float*)d_in[10];
  const float* bq    = (const float*)d_in[11];
  const float* Wk    = (const float*)d_in[12];
  const float* bk    = (const float*)d_in[13];
  const float* Wv    = (const float*)d_in[14];
  const float* bv    = (const float*)d_in[15];
  const float* Wo    = (const float*)d_in[16];
  const float* bo    = (const float*)d_in[17];
  const float* Wfc   = (const float*)d_in[18];
  const float* bfc   = (const float*)d_in[19];
  const float* cq_wc = (const float*)d_in[20];
  const float* cq_wq = (const float*)d_in[21];
  const float* cq_wm = (const float*)d_in[22];
  const float* cq_b  = (const float*)d_in[23];
  float* out = (float*)d_out;
  float* ws = (float*)d_ws;

  float* Cb   = ws;
  float* Qb   = Cb + SZ_C;
  float* t1C  = Qb + SZ_Q;
  float* t1Q  = t1C + SZ_C;
  float* t2C  = t1Q + SZ_Q;
  float* t2Q  = t2C + SZ_C;
  float* t3C  = t2Q + SZ_Q;
  float* t3Q  = t3C + SZ_C;
  float* t4C  = t3Q + SZ_Q;
  float* t4Q  = t4C + SZ_C;
  float* mu0  = t4Q + SZ_Q;
  float* inv0 = mu0 + SSTAT;
  float* mu1  = inv0 + SSTAT;
  float* inv1 = mu1 + SSTAT;
  float* Wcan = inv1 + SSTAT;

  k_transposeW<<<(9 * 16384 + 255) / 256, 256, 0, stream>>>(pw_w, Wo, Wfc, Wq, Wk, Wv, Wcan);
  k_pestats<<<512, 256, 0, stream>>>(ctx, que, Cb, Qb, mu0, inv0);

  for (int i = 0; i < NC; ++i) {
    const float* inC = (i & 1) ? t1C : Cb;
    const float* inQ = (i & 1) ? t1Q : Qb;
    float* oC = (i & 1) ? Cb : t1C;
    float* oQ = (i & 1) ? Qb : t1Q;
    const float* mI = (i & 1) ? mu1 : mu0;
    const float* iI = (i & 1) ? inv1 : inv0;
    float* mO = (i & 1) ? mu0 : mu1;
    float* iO = (i & 1) ? inv0 : inv1;
    k_convgemm<<<512, 256, 0, stream>>>(inC, inQ, oC, oQ,
                                        Wcan + (size_t)i * 16384, pw_b + (size_t)i * DD,
                                        dw_w + (size_t)i * DD * KW, dw_b + (size_t)i * DD,
                                        mI, iI, mO, iO, ln_g, ln_b);
  }
  k_gemm_qkv<<<1536, 256, 0, stream>>>(Cb, Qb, t1C, t1Q, t2C, t2Q, t3C, t3Q,
                                       Wcan, bq, bk, bv, mu0, inv0, ln_g, ln_b);
  k_attn2<<<1536, 256, 0, stream>>>(t1C, t2C, t3C, t1Q, t2Q, t3Q, cmask, qmask, t4C, t4Q);
  k_gemm64<0, 1, 1><<<512, 256, 0, stream>>>(t4C, t4Q, Cb, Qb, Wcan + 4 * 16384, bo,
                                             mu0, inv0, mu1, inv1, ln_g, ln_b);
  k_gemm64<1, 1, 0><<<512, 256, 0, stream>>>(Cb, Qb, Cb, Qb, Wcan + 5 * 16384, bfc,
                                             mu1, inv1, mu0, inv0, ln_g, ln_b);

  // ---- context-query attention ----
  float* C2  = t1C;
  float* Q2  = t1Q;
  float* S   = t2C;
  float* Sr  = t2C + 1638400;
  float* Scb = t3C;
  float* Uu  = t2Q;
  float* cd  = t3Q;
  float* qd  = t4Q;

  k_prep<<<3953, 256, 0, stream>>>(Cb, Qb, C2, Q2, cq_wc, cq_wq, cd, qd);
  k_S2<<<448, 256, 0, stream>>>(C2, Q2, cd, qd, cq_wm, cq_b, S);
  k_smax<<<BB * MM + BB * NN, 64, 0, stream>>>(S, Sr, Scb, cmask, qmask);
  k_U<<<(BB * MM * 32 + 255) / 256, 256, 0, stream>>>(Scb, C2, Uu);
  k_ABtF<<<448, 256, 0, stream>>>(Sr, Q2, Uu, C2, out);
}

// Round 9
// 617.597 us; speedup vs baseline: 1.1892x; 1.0431x over previous
//
#include <hip/hip_runtime.h>
#include <math.h>

#define BB 64
#define DD 128
#define NN 400
#define MM 50
#define HH 8
#define KDIM 16
#define NC 4
#define KW 7

#define SZ_C (BB * DD * NN)   // 3,276,800
#define SZ_Q (BB * DD * MM)   //   409,600
#define SSTAT (BB * NN + BB * MM)  // 28,800; q stats at offset BB*NN

// ---------------- canonical weight transpose: Wcan[m][d][e] ----------------
__global__ void k_transposeW(const float* __restrict__ pw_w, const float* __restrict__ Wo,
                             const float* __restrict__ Wfc, const float* __restrict__ Wq,
                             const float* __restrict__ Wk, const float* __restrict__ Wv,
                             float* __restrict__ Wcan) {
  int idx = blockIdx.x * 256 + threadIdx.x;
  if (idx >= 9 * 16384) return;
  int m = idx >> 14;
  int r = idx & 16383;
  int d = r >> 7, e = r & 127;
  float v;
  if (m < 4) v = pw_w[m * 16384 + e * 128 + d];
  else if (m == 4) v = Wo[d * 128 + e];
  else if (m == 5) v = Wfc[e * 128 + d];
  else {
    const float* W = (m == 6) ? Wq : (m == 7) ? Wk : Wv;
    v = W[((e >> 4) * 128 + d) * 16 + (e & 15)];
  }
  Wcan[idx] = v;
}

// ---------------- fused PE add + LN stats ----------------
__global__ void k_pestats(const float* __restrict__ xC, const float* __restrict__ xQ,
                          float* __restrict__ yC, float* __restrict__ yQ,
                          float* __restrict__ mu, float* __restrict__ inv) {
  int blk = blockIdx.x;
  const float* x; float* y; int L, l0, b, soff;
  if (blk < 448) { b = blk / 7; l0 = (blk % 7) * 64; x = xC; y = yC; L = NN; soff = 0; }
  else { b = blk - 448; l0 = 0; x = xQ; y = yQ; L = MM; soff = BB * NN; }
  int tid = threadIdx.x;
  int ll = tid & 63;
  int dq = tid >> 6;
  int l = l0 + ll;
  __shared__ float s_sum[4][64], s_sq[4][64];
  float sum = 0.f, sq = 0.f;
  if (l < L) {
    const float* px = x + (size_t)b * DD * L + l;
    float* py = y + (size_t)b * DD * L + l;
    for (int d = dq * 32; d < dq * 32 + 32; ++d) {
      int de = d & ~1;
      float freq = __expf((float)de * (-9.210340371976184f / 128.0f));
      float ph = (d & 1) ? 1.5707963267948966f : 0.0f;
      float v = px[(size_t)d * L] + sinf((float)l * freq + ph);
      py[(size_t)d * L] = v;
      sum += v; sq += v * v;
    }
  }
  s_sum[dq][ll] = sum; s_sq[dq][ll] = sq;
  __syncthreads();
  if (dq == 0 && l < L) {
    float ts = s_sum[0][ll] + s_sum[1][ll] + s_sum[2][ll] + s_sum[3][ll];
    float tq = s_sq[0][ll] + s_sq[1][ll] + s_sq[2][ll] + s_sq[3][ll];
    float m = ts * (1.0f / 128.0f);
    float var = (tq - 128.0f * m * m) * (1.0f / 127.0f);
    float sd = sqrtf(fmaxf(var, 0.f));
    mu[soff + b * L + l] = m;
    inv[soff + b * L + l] = 1.0f / (sd + 1e-6f);
  }
}

// ---------------- fused conv layer, 64-col tiles (512 blocks = 2/CU) ----------------
__global__ __launch_bounds__(256, 2) void k_convgemm(
    const float* __restrict__ xC, const float* __restrict__ xQ,
    float* __restrict__ outC, float* __restrict__ outQ,
    const float* __restrict__ Wc, const float* __restrict__ pwb,
    const float* __restrict__ dww, const float* __restrict__ dwb,
    const float* __restrict__ muI, const float* __restrict__ invI,
    float* __restrict__ muO, float* __restrict__ invO,
    const float* __restrict__ g, const float* __restrict__ beta) {
  int blk = blockIdx.x;
  int b = blk >> 3, tile = blk & 7;
  const float* x; float* out; int L, l0, soff;
  if (tile < 7) { x = xC; out = outC; L = NN; l0 = tile * 64; soff = 0; }
  else { x = xQ; out = outQ; L = MM; l0 = 0; soff = BB * NN; }
  __shared__ float Wl[32 * 128];
  __shared__ float Xl[32 * 64];
  __shared__ float Sm[70], Si[70];   // stats halo [l0-3, l0+67)
  int tid = threadIdx.x;
  const float* xb = x + (size_t)b * DD * L;
  for (int t = tid; t < 70; t += 256) {
    int gl = l0 + t - 3;
    bool ok = (gl >= 0 && gl < L);
    Sm[t] = ok ? muI[soff + b * L + gl] : 0.f;
    Si[t] = ok ? invI[soff + b * L + gl] : 0.f;
  }
  float acc[8][4];
  #pragma unroll
  for (int i = 0; i < 8; ++i)
    #pragma unroll
    for (int j = 0; j < 4; ++j) acc[i][j] = 0.f;
  __syncthreads();
  for (int kc = 0; kc < 4; ++kc) {
    int d0 = kc * 32;
    #pragma unroll
    for (int i = 0; i < 4; ++i) {
      int idx = i * 256 + tid;
      ((float4*)Wl)[idx] = ((const float4*)Wc)[(size_t)d0 * 32 + idx];
    }
    #pragma unroll
    for (int r = 0; r < 2; ++r) {
      int k = r * 16 + (tid >> 4);
      int d = d0 + k;
      int c0 = (tid & 15) * 4;
      const float* xrow = xb + (size_t)d * L;
      float gd = g[d], bd = beta[d];
      float wv[7];
      #pragma unroll
      for (int u = 0; u < 7; ++u) wv[u] = dww[d * 7 + u];
      float dbv = dwb[d];
      float xw[10];
      int gbase = l0 + c0 - 3;
      if (gbase >= 1 && gbase + 11 <= L && (((unsigned)(d * L + gbase - 1)) & 3u) == 0u) {
        const float4* p = (const float4*)&xrow[gbase - 1];
        float4 A = p[0], Bv = p[1], Cv = p[2];
        float xr[12] = {A.x, A.y, A.z, A.w, Bv.x, Bv.y, Bv.z, Bv.w, Cv.x, Cv.y, Cv.z, Cv.w};
        #pragma unroll
        for (int s = 0; s < 10; ++s)
          xw[s] = gd * (xr[s + 1] - Sm[c0 + s]) * Si[c0 + s] + bd;
      } else {
        #pragma unroll
        for (int s = 0; s < 10; ++s) {
          int gl = gbase + s;
          float v = 0.f;
          if (gl >= 0 && gl < L)
            v = gd * (xrow[gl] - Sm[c0 + s]) * Si[c0 + s] + bd;
          xw[s] = v;
        }
      }
      float4 o;
      o.x = dbv; o.y = dbv; o.z = dbv; o.w = dbv;
      #pragma unroll
      for (int u = 0; u < 7; ++u) {
        o.x += wv[u] * xw[u];
        o.y += wv[u] * xw[u + 1];
        o.z += wv[u] * xw[u + 2];
        o.w += wv[u] * xw[u + 3];
      }
      *(float4*)&Xl[k * 64 + c0] = o;
    }
    __syncthreads();
    int e0 = (tid >> 4) * 8, cq = (tid & 15) * 4;
    for (int k = 0; k < 32; ++k) {
      const float4* wp = (const float4*)&Wl[k * 128 + e0];
      float4 w0 = wp[0], w1 = wp[1];
      float4 xv = *(const float4*)&Xl[k * 64 + cq];
      float we[8] = {w0.x, w0.y, w0.z, w0.w, w1.x, w1.y, w1.z, w1.w};
      float xe[4] = {xv.x, xv.y, xv.z, xv.w};
      #pragma unroll
      for (int i = 0; i < 8; ++i)
        #pragma unroll
        for (int j = 0; j < 4; ++j) acc[i][j] += we[i] * xe[j];
    }
    __syncthreads();
  }
  int e0 = (tid >> 4) * 8, cq = (tid & 15) * 4;
  float ssum[4], ssq[4];
  #pragma unroll
  for (int j = 0; j < 4; ++j) { ssum[j] = 0.f; ssq[j] = 0.f; }
  #pragma unroll
  for (int i = 0; i < 8; ++i) {
    float bi = pwb[e0 + i];
    float* po = out + ((size_t)b * DD + e0 + i) * L;
    const float* pr = xb + (size_t)(e0 + i) * L;
    #pragma unroll
    for (int j = 0; j < 4; ++j) {
      int l = l0 + cq + j;
      if (l < L) {
        float v = fmaxf(acc[i][j] + bi, 0.f) + pr[l];
        po[l] = v;
        ssum[j] += v; ssq[j] += v * v;
      }
    }
  }
  int grp = tid >> 4;
  #pragma unroll
  for (int j = 0; j < 4; ++j) {
    Xl[grp * 64 + cq + j] = ssum[j];
    Wl[grp * 64 + cq + j] = ssq[j];
  }
  __syncthreads();
  if (tid < 64) {
    int l = l0 + tid;
    if (l < L) {
      float ts = 0.f, tq = 0.f;
      #pragma unroll
      for (int gg = 0; gg < 16; ++gg) { ts += Xl[gg * 64 + tid]; tq += Wl[gg * 64 + tid]; }
      float m = ts * (1.0f / 128.0f);
      float var = (tq - 128.0f * m * m) * (1.0f / 127.0f);
      float sd = sqrtf(fmaxf(var, 0.f));
      muO[soff + b * L + l] = m;
      invO[soff + b * L + l] = 1.0f / (sd + 1e-6f);
    }
  }
}

// ---------------- 128x64 GEMM tiles, 512 blocks ----------------
// LNF: LN during staging. ACT: 0=write, 1=+residual. STATS: LN stats epilogue.
// TRANS: additionally emit transposed output Y2[b,l,e] + dot-with-weight dd[b,l]
// (replaces the old k_prep pass: data is already in registers here).
template <int LNF, int ACT, int STATS, int TRANS>
__global__ __launch_bounds__(256) void k_gemm64(
    const float* __restrict__ xC, const float* __restrict__ xQ,
    float* __restrict__ outC, float* __restrict__ outQ,
    const float* __restrict__ Wc, const float* __restrict__ bias,
    const float* __restrict__ mu, const float* __restrict__ inv,
    float* __restrict__ muO, float* __restrict__ invO,
    const float* __restrict__ g, const float* __restrict__ beta,
    float* __restrict__ C2o, float* __restrict__ Q2o,
    float* __restrict__ cdo, float* __restrict__ qdo,
    const float* __restrict__ wc, const float* __restrict__ wq) {
  int blk = blockIdx.x;
  int b = blk >> 3, tile = blk & 7;
  const float* x; float* out; int L, l0, soff;
  if (tile < 7) { x = xC; out = outC; L = NN; l0 = tile * 64; soff = 0; }
  else { x = xQ; out = outQ; L = MM; l0 = 0; soff = BB * NN; }
  // TRANS re-uses Wl/Xl as two 64x68 transpose buffers (stride 68: 2-way banks, free)
  __shared__ float Wl[TRANS ? 64 * 68 : 32 * 128];
  __shared__ float Xl[TRANS ? 64 * 68 : 32 * 64];
  int tid = threadIdx.x;
  float acc[8][4];
  #pragma unroll
  for (int i = 0; i < 8; ++i)
    #pragma unroll
    for (int j = 0; j < 4; ++j) acc[i][j] = 0.f;
  const float* xb = x + (size_t)b * DD * L;
  const float* pmu = mu + soff + b * L;
  const float* pin = inv + soff + b * L;
  for (int kc = 0; kc < 4; ++kc) {
    int d0 = kc * 32;
    #pragma unroll
    for (int i = 0; i < 4; ++i) {
      int idx = i * 256 + tid;
      ((float4*)Wl)[idx] = ((const float4*)Wc)[(size_t)d0 * 32 + idx];
    }
    #pragma unroll
    for (int t = 0; t < 8; ++t) {
      int idx = t * 256 + tid;
      int k = idx >> 6, l = idx & 63;
      float v = 0.f;
      int gl = l0 + l;
      if (gl < L) {
        v = xb[(size_t)(d0 + k) * L + gl];
        if (LNF) v = g[d0 + k] * (v - pmu[gl]) * pin[gl] + beta[d0 + k];
      }
      Xl[idx] = v;
    }
    __syncthreads();
    int e0 = (tid >> 4) * 8, cq = (tid & 15) * 4;
    for (int k = 0; k < 32; ++k) {
      const float4* wp = (const float4*)&Wl[k * 128 + e0];
      float4 w0 = wp[0], w1 = wp[1];
      float4 xv = *(const float4*)&Xl[k * 64 + cq];
      float we[8] = {w0.x, w0.y, w0.z, w0.w, w1.x, w1.y, w1.z, w1.w};
      float xe[4] = {xv.x, xv.y, xv.z, xv.w};
      #pragma unroll
      for (int i = 0; i < 8; ++i)
        #pragma unroll
        for (int j = 0; j < 4; ++j) acc[i][j] += we[i] * xe[j];
    }
    __syncthreads();
  }
  int e0 = (tid >> 4) * 8, cq = (tid & 15) * 4;
  float ssum[4], ssq[4];
  #pragma unroll
  for (int j = 0; j < 4; ++j) { ssum[j] = 0.f; ssq[j] = 0.f; }
  #pragma unroll
  for (int i = 0; i < 8; ++i) {
    float bi = bias[e0 + i];
    float* po = out + ((size_t)b * DD + e0 + i) * L;
    #pragma unroll
    for (int j = 0; j < 4; ++j) {
      int l = l0 + cq + j;
      if (l < L) {
        float v = acc[i][j] + bi;
        if (ACT != 0) v += po[l];
        po[l] = v;
        if (STATS) { ssum[j] += v; ssq[j] += v * v; }
        if (TRANS) {
          float* T = (e0 < 64) ? Wl : Xl;
          T[(cq + j) * 68 + (e0 & 63) + i] = v;
        }
      }
    }
  }
  if (STATS) {
    int grp = tid >> 4;
    #pragma unroll
    for (int j = 0; j < 4; ++j) {
      Xl[grp * 64 + cq + j] = ssum[j];
      Wl[grp * 64 + cq + j] = ssq[j];
    }
    __syncthreads();
    if (tid < 64) {
      int l = l0 + tid;
      if (l < L) {
        float ts = 0.f, tq = 0.f;
        #pragma unroll
        for (int gg = 0; gg < 16; ++gg) { ts += Xl[gg * 64 + tid]; tq += Wl[gg * 64 + tid]; }
        float m = ts * (1.0f / 128.0f);
        float var = (tq - 128.0f * m * m) * (1.0f / 127.0f);
        float sd = sqrtf(fmaxf(var, 0.f));
        muO[soff + b * L + l] = m;
        invO[soff + b * L + l] = 1.0f / (sd + 1e-6f);
      }
    }
  }
  if (TRANS) {
    __syncthreads();
    // cooperative coalesced write of Y2[b, l, 0..127] + dot(dd)
    int r = tid >> 2, seg = tid & 3;      // 64 rows x 4 e-segments (32 e each)
    int gl = l0 + r;
    const float* wsel = (tile < 7) ? wc : wq;
    float* Y2 = (tile < 7) ? C2o : Q2o;
    float* dd = (tile < 7) ? cdo : qdo;
    float part = 0.f;
    if (gl < L) {
      float4* dst = (float4*)(Y2 + ((size_t)b * L + gl) * 128);
      #pragma unroll
      for (int q8 = 0; q8 < 8; ++q8) {
        int e = seg * 32 + q8 * 4;
        const float* T = (e < 64) ? Wl : Xl;
        float4 v4 = *(const float4*)&T[r * 68 + (e & 63)];
        dst[seg * 8 + q8] = v4;
        float4 w4 = *(const float4*)&wsel[e];
        part += v4.x * w4.x + v4.y * w4.y + v4.z * w4.z + v4.w * w4.w;
      }
    }
    part += __shfl_xor(part, 1);
    part += __shfl_xor(part, 2);
    if (gl < L && seg == 0) dd[b * L + gl] = part;
  }
}

// ---------------- fused QKV GEMM: 3 x 512 blocks ----------------
__global__ __launch_bounds__(256) void k_gemm_qkv(
    const float* __restrict__ xC, const float* __restrict__ xQ,
    float* __restrict__ o1C, float* __restrict__ o1Q,
    float* __restrict__ o2C, float* __restrict__ o2Q,
    float* __restrict__ o3C, float* __restrict__ o3Q,
    const float* __restrict__ Wcan,
    const float* __restrict__ bq, const float* __restrict__ bk, const float* __restrict__ bv,
    const float* __restrict__ mu, const float* __restrict__ inv,
    const float* __restrict__ g, const float* __restrict__ beta) {
  int blk0 = blockIdx.x;
  int grp = blk0 >> 9;
  int blk = blk0 & 511;
  const float* Wc = Wcan + (size_t)(6 + grp) * 16384;
  const float* bias = (grp == 0) ? bq : (grp == 1) ? bk : bv;
  float* oC = (grp == 0) ? o1C : (grp == 1) ? o2C : o3C;
  float* oQ = (grp == 0) ? o1Q : (grp == 1) ? o2Q : o3Q;
  int b = blk >> 3, tile = blk & 7;
  const float* x; float* out; int L, l0, soff;
  if (tile < 7) { x = xC; out = oC; L = NN; l0 = tile * 64; soff = 0; }
  else { x = xQ; out = oQ; L = MM; l0 = 0; soff = BB * NN; }
  __shared__ float Wl[32 * 128];
  __shared__ float Xl[32 * 64];
  int tid = threadIdx.x;
  float acc[8][4];
  #pragma unroll
  for (int i = 0; i < 8; ++i)
    #pragma unroll
    for (int j = 0; j < 4; ++j) acc[i][j] = 0.f;
  const float* xb = x + (size_t)b * DD * L;
  const float* pmu = mu + soff + b * L;
  const float* pin = inv + soff + b * L;
  for (int kc = 0; kc < 4; ++kc) {
    int d0 = kc * 32;
    #pragma unroll
    for (int i = 0; i < 4; ++i) {
      int idx = i * 256 + tid;
      ((float4*)Wl)[idx] = ((const float4*)Wc)[(size_t)d0 * 32 + idx];
    }
    #pragma unroll
    for (int t = 0; t < 8; ++t) {
      int idx = t * 256 + tid;
      int k = idx >> 6, l = idx & 63;
      float v = 0.f;
      int gl = l0 + l;
      if (gl < L) {
        v = xb[(size_t)(d0 + k) * L + gl];
        v = g[d0 + k] * (v - pmu[gl]) * pin[gl] + beta[d0 + k];
      }
      Xl[idx] = v;
    }
    __syncthreads();
    int e0 = (tid >> 4) * 8, cq = (tid & 15) * 4;
    for (int k = 0; k < 32; ++k) {
      const float4* wp = (const float4*)&Wl[k * 128 + e0];
      float4 w0 = wp[0], w1 = wp[1];
      float4 xv = *(const float4*)&Xl[k * 64 + cq];
      float we[8] = {w0.x, w0.y, w0.z, w0.w, w1.x, w1.y, w1.z, w1.w};
      float xe[4] = {xv.x, xv.y, xv.z, xv.w};
      #pragma unroll
      for (int i = 0; i < 8; ++i)
        #pragma unroll
        for (int j = 0; j < 4; ++j) acc[i][j] += we[i] * xe[j];
    }
    __syncthreads();
  }
  int e0 = (tid >> 4) * 8, cq = (tid & 15) * 4;
  #pragma unroll
  for (int i = 0; i < 8; ++i) {
    float bi = bias[e0 + i];
    float* po = out + ((size_t)b * DD + e0 + i) * L;
    #pragma unroll
    for (int j = 0; j < 4; ++j) {
      int l = l0 + cq + j;
      if (l < L) po[l] = acc[i][j] + bi;
    }
  }
}

// ---------------- attention (R5 champion: 1q/thread, ctx split, 53 KB LDS) ----------------
// Scalar-fp32 floor verified across 4 structures (R1/R5/R6/R7): ~163 us. FROZEN.
__global__ __launch_bounds__(256) void k_attn2(
    const float* __restrict__ qC, const float* __restrict__ kC, const float* __restrict__ vC,
    const float* __restrict__ qQ, const float* __restrict__ kQ, const float* __restrict__ vQ,
    const float* __restrict__ cmask, const float* __restrict__ qmask,
    float* __restrict__ oC, float* __restrict__ oQ) {
  int blk = blockIdx.x;
  const float *qp, *kp, *vp, *mk; float* op; int L, b, h, q0, qcnt;
  if (blk < 1024) {
    b = blk >> 4; h = (blk >> 1) & 7; int half = blk & 1;
    qp = qC; kp = kC; vp = vC; mk = cmask; op = oC; L = NN;
    q0 = half * 256; qcnt = half ? (NN - 256) : 256;
  } else {
    int bb = blk - 1024; b = bb >> 3; h = bb & 7;
    qp = qQ; kp = kQ; vp = vQ; mk = qmask; op = oQ; L = MM;
    q0 = 0; qcnt = MM;
  }
  __shared__ float Kl[NN * KDIM];
  __shared__ float Vl[NN * KDIM];
  __shared__ float Ml[NN];
  int tid = threadIdx.x;
  size_t base = ((size_t)b * DD + h * KDIM) * L;
  int KP = (L + 7) & ~7;
  for (int idx = tid; idx < KDIM * L; idx += 256) {
    int t = idx / L, j = idx - t * L;
    Kl[j * KDIM + t] = kp[base + (size_t)t * L + j];
    Vl[j * KDIM + t] = vp[base + (size_t)t * L + j];
  }
  for (int idx = tid; idx < (KP - L) * KDIM; idx += 256) {
    int j = L + (idx >> 4), t = idx & 15;
    Kl[j * KDIM + t] = 0.f; Vl[j * KDIM + t] = 0.f;
  }
  for (int j = tid; j < KP; j += 256)
    Ml[j] = (j < L) ? -1e30f * (1.0f - mk[b * L + j]) : -1e30f;
  __syncthreads();
  if (tid >= qcnt) return;

  int i = q0 + tid;
  float q[KDIM];
  #pragma unroll
  for (int t = 0; t < KDIM; ++t) q[t] = qp[base + (size_t)t * L + i] * 0.25f;
  float m = -1e30f, ls = 0.f;
  float acc[KDIM];
  #pragma unroll
  for (int t = 0; t < KDIM; ++t) acc[t] = 0.f;
  for (int j0 = 0; j0 < KP; j0 += 8) {
    const float4* mp = (const float4*)&Ml[j0];
    float4 ma0 = mp[0], ma1 = mp[1];
    float mav[8] = {ma0.x, ma0.y, ma0.z, ma0.w, ma1.x, ma1.y, ma1.z, ma1.w};
    float s[8];
    #pragma unroll
    for (int jj = 0; jj < 8; ++jj) {
      const float4* kf = (const float4*)&Kl[(j0 + jj) * KDIM];
      float4 k0 = kf[0], k1 = kf[1], k2 = kf[2], k3 = kf[3];
      float da = q[0] * k0.x + q[1] * k0.y + q[2] * k0.z + q[3] * k0.w
               + q[4] * k1.x + q[5] * k1.y + q[6] * k1.z + q[7] * k1.w;
      float db = q[8] * k2.x + q[9] * k2.y + q[10] * k2.z + q[11] * k2.w
               + q[12] * k3.x + q[13] * k3.y + q[14] * k3.z + q[15] * k3.w;
      s[jj] = da + db + mav[jj];
    }
    float cm = s[0];
    #pragma unroll
    for (int jj = 1; jj < 8; ++jj) cm = fmaxf(cm, s[jj]);
    if (cm > m) {  // exact: skipped branch would multiply by exp(0)=1
      float sc = __expf(m - cm);
      ls *= sc;
      #pragma unroll
      for (int t = 0; t < KDIM; ++t) acc[t] *= sc;
      m = cm;
    }
    #pragma unroll
    for (int jj = 0; jj < 8; ++jj) {
      float p = __expf(s[jj] - m);
      ls += p;
      const float4* vf = (const float4*)&Vl[(j0 + jj) * KDIM];
      float4 v0 = vf[0], v1 = vf[1], v2 = vf[2], v3 = vf[3];
      acc[0] += p * v0.x;  acc[1] += p * v0.y;  acc[2] += p * v0.z;  acc[3] += p * v0.w;
      acc[4] += p * v1.x;  acc[5] += p * v1.y;  acc[6] += p * v1.z;  acc[7] += p * v1.w;
      acc[8] += p * v2.x;  acc[9] += p * v2.y;  acc[10] += p * v2.z; acc[11] += p * v2.w;
      acc[12] += p * v3.x; acc[13] += p * v3.y; acc[14] += p * v3.z; acc[15] += p * v3.w;
    }
  }
  float invl = 1.0f / ls;
  #pragma unroll
  for (int t = 0; t < KDIM; ++t)
    op[base + (size_t)t * L + i] = acc[t] * invl;
}

// ---------------- S tiled: block per (b, 64-n tile); C2*wm and Q2 in LDS ----------------
__global__ __launch_bounds__(256) void k_S2(
    const float* __restrict__ C2, const float* __restrict__ Q2,
    const float* __restrict__ cd, const float* __restrict__ qd,
    const float* __restrict__ wm, const float* __restrict__ bias,
    float* __restrict__ S) {
  int blk = blockIdx.x;            // 448 = 64 b x 7 ntiles
  int b = blk / 7, nt = blk % 7;
  int n0 = nt * 64;
  int nv = NN - n0; if (nv > 64) nv = 64;
  __shared__ float Cw[64 * 132];
  __shared__ float Ql[52 * 132];
  __shared__ float cdl[64];
  __shared__ float qdl[50];
  int tid = threadIdx.x;
  const float4* c4g = (const float4*)(C2 + (size_t)b * NN * DD);
  const float4* q4g = (const float4*)(Q2 + (size_t)b * MM * DD);
  const float4* w4 = (const float4*)wm;
  for (int i = tid; i < 64 * 32; i += 256) {
    int n = i >> 5, d4 = i & 31;
    float4 v = {0.f, 0.f, 0.f, 0.f};
    if (n < nv) {
      float4 c = c4g[(size_t)(n0 + n) * 32 + d4];
      float4 w = w4[d4];
      v.x = c.x * w.x; v.y = c.y * w.y; v.z = c.z * w.z; v.w = c.w * w.w;
    }
    *(float4*)&Cw[n * 132 + d4 * 4] = v;
  }
  for (int i = tid; i < 52 * 32; i += 256) {
    int m = i >> 5, d4 = i & 31;
    float4 v = {0.f, 0.f, 0.f, 0.f};
    if (m < MM) v = q4g[(size_t)m * 32 + d4];
    *(float4*)&Ql[m * 132 + d4 * 4] = v;
  }
  if (tid < 64) cdl[tid] = (tid < nv) ? cd[b * NN + n0 + tid] : 0.f;
  if (tid >= 64 && tid < 114) qdl[tid - 64] = qd[b * MM + (tid - 64)];
  __syncthreads();
  int n = tid >> 2, mg = tid & 3;
  int m0 = mg * 13;                 // 13,13,13,11 m's per thread
  float acc[13];
  #pragma unroll
  for (int k = 0; k < 13; ++k) acc[k] = 0.f;
  const float* cp = &Cw[n * 132];
  for (int d4 = 0; d4 < 32; ++d4) {
    float4 c = *(const float4*)&cp[d4 * 4];
    #pragma unroll
    for (int k = 0; k < 13; ++k) {
      float4 q = *(const float4*)&Ql[(m0 + k) * 132 + d4 * 4];
      acc[k] += c.x * q.x + c.y * q.y + c.z * q.z + c.w * q.w;
    }
  }
  if (n < nv) {
    float add = cdl[n] + bias[0];
    float* ps = S + ((size_t)b * NN + n0 + n) * MM + m0;
    #pragma unroll
    for (int k = 0; k < 13; ++k) {
      int m = m0 + k;
      if (m < MM) ps[k] = acc[k] + add + qdl[m];
    }
  }
}

// ---------------- merged softmaxes + fused U ----------------
// col blocks (blk < BB*MM): softmax over n -> LDS, then U[b,m,:] = Sc . C2 directly
// (Sc never materialized to global). row blocks: softmax over m -> Sr.
__global__ void k_smaxU(const float* __restrict__ S, float* __restrict__ Sr,
                        const float* __restrict__ cmask, const float* __restrict__ qmask,
                        const float* __restrict__ C2, float* __restrict__ U) {
  int blk = blockIdx.x;
  int tid = threadIdx.x;
  if (blk < BB * MM) {
    int b = blk / MM;
    int mcol = blk % MM;
    __shared__ float Sl[NN];
    float vals[7];
    float mx = -1e30f;
    #pragma unroll
    for (int c = 0; c < 7; ++c) {
      int n = tid + c * 64;
      float s = -1e30f;
      if (n < NN)
        s = S[((size_t)b * NN + n) * MM + mcol] - 1e30f * (1.0f - cmask[b * NN + n]);
      vals[c] = s;
      mx = fmaxf(mx, s);
    }
    #pragma unroll
    for (int off = 1; off < 64; off <<= 1) mx = fmaxf(mx, __shfl_xor(mx, off));
    float sum = 0.f;
    #pragma unroll
    for (int c = 0; c < 7; ++c) { vals[c] = __expf(vals[c] - mx); sum += vals[c]; }
    #pragma unroll
    for (int off = 1; off < 64; off <<= 1) sum += __shfl_xor(sum, off);
    float inv = 1.0f / sum;
    #pragma unroll
    for (int c = 0; c < 7; ++c) {
      int n = tid + c * 64;
      if (n < NN) Sl[n] = vals[c] * inv;
    }
    __syncthreads();
    // U[b,mcol,d]: thread owns float2 at d = 2*tid
    const float2* c2 = (const float2*)(C2 + (size_t)b * NN * DD) + tid;
    float2 a = {0.f, 0.f};
    #pragma unroll 4
    for (int kk = 0; kk < NN; ++kk) {
      float s = Sl[kk];
      float2 c = c2[(size_t)kk * 64];
      a.x += s * c.x; a.y += s * c.y;
    }
    ((float2*)(U + ((size_t)b * MM + mcol) * DD))[tid] = a;
  } else {
    int bn = blk - BB * MM;
    int b = bn / NN;
    float s = -1e30f;
    if (tid < MM)
      s = S[(size_t)bn * MM + tid] - 1e30f * (1.0f - qmask[b * MM + tid]);
    float mx = s;
    #pragma unroll
    for (int off = 1; off < 64; off <<= 1) mx = fmaxf(mx, __shfl_xor(mx, off));
    float e = (tid < MM) ? __expf(s - mx) : 0.f;
    float sum = e;
    #pragma unroll
    for (int off = 1; off < 64; off <<= 1) sum += __shfl_xor(sum, off);
    if (tid < MM) Sr[(size_t)bn * MM + tid] = e / sum;
  }
}

// ---------------- fused A/Bt + final concat; LDS-staged Q2/Uu/Sr ----------------
__global__ __launch_bounds__(256) void k_ABtF(
    const float* __restrict__ Sr, const float* __restrict__ Q2,
    const float* __restrict__ Uu, const float* __restrict__ C2,
    float* __restrict__ out) {
  int blk = blockIdx.x;
  int b = blk / 7, nt = blk % 7;
  int n0 = nt * 64;
  int nv = NN - n0; if (nv > 64) nv = 64;
  __shared__ float Ql[MM * 128];
  __shared__ float Ul[MM * 128];
  __shared__ float Sl[64 * MM];
  int tid = threadIdx.x;
  const float4* q4 = (const float4*)(Q2 + (size_t)b * MM * DD);
  const float4* u4 = (const float4*)(Uu + (size_t)b * MM * DD);
  for (int i = tid; i < MM * 32; i += 256) {
    ((float4*)Ql)[i] = q4[i];
    ((float4*)Ul)[i] = u4[i];
  }
  for (int i = tid; i < 64 * MM; i += 256) {
    int n = i / MM;
    Sl[i] = (n < nv) ? Sr[((size_t)b * NN + n0 + n) * MM + (i - n * MM)] : 0.f;
  }
  __syncthreads();
  int n = tid >> 2;
  if (n >= nv) return;
  int d04 = (tid & 3) * 8;
  float4 accA[8], accB[8];
  #pragma unroll
  for (int r = 0; r < 8; ++r) {
    accA[r] = {0.f, 0.f, 0.f, 0.f};
    accB[r] = {0.f, 0.f, 0.f, 0.f};
  }
  const float* sp = &Sl[n * MM];
  for (int m = 0; m < MM; ++m) {
    float s = sp[m];
    const float4* qp = (const float4*)&Ql[m * 128] + d04;
    const float4* up = (const float4*)&Ul[m * 128] + d04;
    #pragma unroll
    for (int r = 0; r < 8; ++r) {
      float4 q = qp[r], u = up[r];
      accA[r].x += s * q.x; accA[r].y += s * q.y; accA[r].z += s * q.z; accA[r].w += s * q.w;
      accB[r].x += s * u.x; accB[r].y += s * u.y; accB[r].z += s * u.z; accB[r].w += s * u.w;
    }
  }
  int gn = n0 + n;
  const float4* c4 = (const float4*)(C2 + ((size_t)b * NN + gn) * DD) + d04;
  float4* po = (float4*)(out + (size_t)(b * NN + gn) * 512);
  #pragma unroll
  for (int r = 0; r < 8; ++r) {
    float4 c = c4[r];
    float4 a = accA[r], bt = accB[r];
    po[d04 + r] = c;
    po[32 + d04 + r] = a;
    float4 ca = {c.x * a.x, c.y * a.y, c.z * a.z, c.w * a.w};
    po[64 + d04 + r] = ca;
    float4 cb = {c.x * bt.x, c.y * bt.y, c.z * bt.z, c.w * bt.w};
    po[96 + d04 + r] = cb;
  }
}

extern "C" void kernel_launch(void* const* d_in, const int* in_sizes, int n_in,
                              void* d_out, int out_size, void* d_ws, size_t ws_size,
                              hipStream_t stream) {
  (void)in_sizes; (void)n_in; (void)out_size; (void)ws_size;
  const float* ctx   = (const float*)d_in[0];
  const float* que   = (const float*)d_in[1];
  const float* cmask = (const float*)d_in[2];
  const float* qmask = (const float*)d_in[3];
  const float* ln_g  = (const float*)d_in[4];
  const float* ln_b  = (const float*)d_in[5];
  const float* dw_w  = (const float*)d_in[6];
  const float* dw_b  = (const float*)d_in[7];
  const float* pw_w  = (const float*)d_in[8];
  const float* pw_b  = (const float*)d_in[9];
  const float* Wq    = (const float*)d_in[10];
  const float* bq    = (const float*)d_in[11];
  const float* Wk    = (const float*)d_in[12];
  const float* bk    = (const float*)d_in[13];
  const float* Wv    = (const float*)d_in[14];
  const float* bv    = (const float*)d_in[15];
  const float* Wo    = (const float*)d_in[16];
  const float* bo    = (const float*)d_in[17];
  const float* Wfc   = (const float*)d_in[18];
  const float* bfc   = (const float*)d_in[19];
  const float* cq_wc = (const float*)d_in[20];
  const float* cq_wq = (const float*)d_in[21];
  const float* cq_wm = (const float*)d_in[22];
  const float* cq_b  = (const float*)d_in[23];
  float* out = (float*)d_out;
  float* ws = (float*)d_ws;

  float* Cb   = ws;
  float* Qb   = Cb + SZ_C;
  float* t1C  = Qb + SZ_Q;
  float* t1Q  = t1C + SZ_C;
  float* t2C  = t1Q + SZ_Q;
  float* t2Q  = t2C + SZ_C;
  float* t3C  = t2Q + SZ_Q;
  float* t3Q  = t3C + SZ_C;
  float* t4C  = t3Q + SZ_Q;
  float* t4Q  = t4C + SZ_C;
  float* mu0  = t4Q + SZ_Q;
  float* inv0 = mu0 + SSTAT;
  float* mu1  = inv0 + SSTAT;
  float* inv1 = mu1 + SSTAT;
  float* Wcan = inv1 + SSTAT;

  k_transposeW<<<(9 * 16384 + 255) / 256, 256, 0, stream>>>(pw_w, Wo, Wfc, Wq, Wk, Wv, Wcan);
  k_pestats<<<512, 256, 0, stream>>>(ctx, que, Cb, Qb, mu0, inv0);

  for (int i = 0; i < NC; ++i) {
    const float* inC = (i & 1) ? t1C : Cb;
    const float* inQ = (i & 1) ? t1Q : Qb;
    float* oC = (i & 1) ? Cb : t1C;
    float* oQ = (i & 1) ? Qb : t1Q;
    const float* mI = (i & 1) ? mu1 : mu0;
    const float* iI = (i & 1) ? inv1 : inv0;
    float* mO = (i & 1) ? mu0 : mu1;
    float* iO = (i & 1) ? inv0 : inv1;
    k_convgemm<<<512, 256, 0, stream>>>(inC, inQ, oC, oQ,
                                        Wcan + (size_t)i * 16384, pw_b + (size_t)i * DD,
                                        dw_w + (size_t)i * DD * KW, dw_b + (size_t)i * DD,
                                        mI, iI, mO, iO, ln_g, ln_b);
  }
  k_gemm_qkv<<<1536, 256, 0, stream>>>(Cb, Qb, t1C, t1Q, t2C, t2Q, t3C, t3Q,
                                       Wcan, bq, bk, bv, mu0, inv0, ln_g, ln_b);
  k_attn2<<<1536, 256, 0, stream>>>(t1C, t2C, t3C, t1Q, t2Q, t3Q, cmask, qmask, t4C, t4Q);

  // ---- CQ-attention buffers ----
  float* C2  = t1C;
  float* Q2  = t1Q;
  float* S   = t2C;
  float* Sr  = t2C + 1638400;
  float* Uu  = t2Q;
  float* cd  = t3Q;
  float* qd  = t4Q + SZ_Q - BB * MM;  // tail of t4Q (free after Wo gemm reads t4)

  // Wo projection: +residual into Cb, stats -> mu1/inv1
  k_gemm64<0, 1, 1, 0><<<512, 256, 0, stream>>>(t4C, t4Q, Cb, Qb, Wcan + 4 * 16384, bo,
                                                mu0, inv0, mu1, inv1, ln_g, ln_b,
                                                nullptr, nullptr, nullptr, nullptr,
                                                nullptr, nullptr);
  // FFN: LN(mu1) + GEMM + residual in-place on Cb; TRANS epilogue emits
  // C2/Q2 (transposed) + cd/qd (dot with cq weights) -- replaces k_prep.
  k_gemm64<1, 1, 0, 1><<<512, 256, 0, stream>>>(Cb, Qb, Cb, Qb, Wcan + 5 * 16384, bfc,
                                                mu1, inv1, mu0, inv0, ln_g, ln_b,
                                                C2, Q2, cd, qd, cq_wc, cq_wq);

  k_S2<<<448, 256, 0, stream>>>(C2, Q2, cd, qd, cq_wm, cq_b, S);
  k_smaxU<<<BB * MM + BB * NN, 64, 0, stream>>>(S, Sr, cmask, qmask, C2, Uu);
  k_ABtF<<<448, 256, 0, stream>>>(Sr, Q2, Uu, C2, out);
}